// Round 4
// baseline (3700.629 us; speedup 1.0000x reference)
//
#include <hip/hip_runtime.h>
#include <hip/hip_bf16.h>

#define DEV __device__ __forceinline__

typedef unsigned short u16;
typedef __attribute__((ext_vector_type(8))) short short8;
typedef __attribute__((ext_vector_type(4))) float floatx4;

DEV float gelu_f(float x){ return 0.5f*x*(1.0f+erff(x*0.7071067811865476f)); }

DEV u16 f2bf(float x){
  union { __hip_bfloat16 h; u16 u; } cv;
  cv.h = __float2bfloat16(x);
  return cv.u;
}
DEV float bf2f(u16 u){
  union { unsigned int u32; float f; } cv;
  cv.u32 = ((unsigned int)u) << 16;
  return cv.f;
}
DEV void split2(float v, u16* H, u16* L, long long i){
  u16 h = f2bf(v); H[i] = h; L[i] = f2bf(v - bf2f(h));
}

// async global->LDS 16B per lane; lds dest = wave-uniform base + lane*16
DEV void stage16(const u16* g, u16* lwave, int lane){
#if __has_builtin(__builtin_amdgcn_global_load_lds)
  __builtin_amdgcn_global_load_lds((const __attribute__((address_space(1))) void*)g,
                                   (__attribute__((address_space(3))) void*)lwave, 16, 0, 0);
#else
  *(short8*)(lwave + (long long)lane*8) = *(const short8*)g;
#endif
}

DEV float blockReduceSum(float v){
  __shared__ float red[4];
  int lane = threadIdx.x & 63, wid = threadIdx.x >> 6;
  #pragma unroll
  for (int off=32; off>0; off>>=1) v += __shfl_down(v, off, 64);
  __syncthreads();
  if (lane==0) red[wid]=v;
  __syncthreads();
  return red[0]+red[1]+red[2]+red[3];
}
DEV float blockReduceMax(float v){
  __shared__ float redm[4];
  int lane = threadIdx.x & 63, wid = threadIdx.x >> 6;
  #pragma unroll
  for (int off=32; off>0; off>>=1) v = fmaxf(v, __shfl_down(v, off, 64));
  __syncthreads();
  if (lane==0) redm[wid]=v;
  __syncthreads();
  return fmaxf(fmaxf(redm[0],redm[1]),fmaxf(redm[2],redm[3]));
}

// ---------------------------------------------------------------------------
// bf16x3 MFMA GEMM on pre-split hi/lo operands.
// A: M x K rows (lda), B: N x K rows (ldb), both as separate H/L u16 arrays.
// 2-phase double-buffered pipeline (T3-min): prologue stages slab 0; each
// iter issues next slab's global_load_lds FIRST, then computes current slab,
// then one __syncthreads() (vmcnt(0) drain pays only residual latency).
// MFMA order per accumulator identical to prior rounds -> bit-identical.
// Epilogue: v = scale*acc + bias -> act -> +resid; writes f32 C and/or H/L
// pair and/or f32 mirror. Two-level batch via blockIdx.z = b1*B2+b2.
// Call sites guarantee M%BM==0, N%BN==0, K%64==0.
// ---------------------------------------------------------------------------
template<int BM, int BN>
__global__ __launch_bounds__(256) void mgemm(
    const u16* __restrict__ AH, const u16* __restrict__ AL,
    const u16* __restrict__ BH, const u16* __restrict__ BL,
    float* __restrict__ C, u16* __restrict__ CH, u16* __restrict__ CL,
    const float* __restrict__ bias, const float* __restrict__ resid,
    float* __restrict__ mirror,
    int K, int lda, int ldb, int ldc,
    long long sA1, long long sA2, long long sB1, long long sB2,
    long long sC1, long long sC2, int B2, float scale, int act)
{
  const int b1 = blockIdx.z / B2, b2 = blockIdx.z % B2;
  const long long aOff = b1*sA1 + b2*sA2;
  const long long bOff = b1*sB1 + b2*sB2;
  const long long cOff = b1*sC1 + b2*sC2;
  AH += aOff; AL += aOff; BH += bOff; BL += bOff;
  if (C) C += cOff;
  if (CH){ CH += cOff; CL += cOff; }
  if (resid) resid += cOff;
  if (mirror) mirror += cOff;

  const int m0 = blockIdx.y*BM, n0 = blockIdx.x*BN;
  const int tid = threadIdx.x, lane = tid & 63, wid = tid >> 6;
  const int ln15 = lane & 15, quad = lane >> 4;
  constexpr int WM = BM/2, WN = BN/2, FM = WM/16, FN = WN/16;
  constexpr int RWA = BM/4, RWB = BN/4;   // staging rows per wave (per slab)
  constexpr int NIA = BM/64, NIB = BN/64; // staging insts per wave per stream
  const int wr = wid >> 1, wc = wid & 1;

  __shared__ u16 AsH[2][BM*32];
  __shared__ u16 AsL[2][BM*32];
  __shared__ u16 BsH[2][BN*32];
  __shared__ u16 BsL[2][BN*32];

  floatx4 acc[FM][FN];
  #pragma unroll
  for (int a=0;a<FM;++a)
    #pragma unroll
    for (int b=0;b<FN;++b) acc[a][b] = (floatx4){0.f,0.f,0.f,0.f};

  // per-lane global staging pointers; LDS slot for lane = wavebase + lane*16B
  const int rA = wid*RWA + (lane >> 2), cA = (lane & 3)*8;
  const int rB = wid*RWB + (lane >> 2), cB = (lane & 3)*8;
  const u16* pAH = AH + (long long)(m0 + rA)*lda + cA;
  const u16* pAL = AL + (long long)(m0 + rA)*lda + cA;
  const u16* pBH = BH + (long long)(n0 + rB)*ldb + cB;
  const u16* pBL = BL + (long long)(n0 + rB)*ldb + cB;
  const int lofsA = wid*RWA*32;
  const int lofsB = wid*RWB*32;

  // prologue: stage slab 0 into buffer 0, full drain at barrier
  #pragma unroll
  for (int j=0;j<NIA;++j){
    stage16(pAH + (long long)j*16*lda, &AsH[0][lofsA + j*512], lane);
    stage16(pAL + (long long)j*16*lda, &AsL[0][lofsA + j*512], lane);
  }
  #pragma unroll
  for (int j=0;j<NIB;++j){
    stage16(pBH + (long long)j*16*ldb, &BsH[0][lofsB + j*512], lane);
    stage16(pBL + (long long)j*16*ldb, &BsL[0][lofsB + j*512], lane);
  }
  __syncthreads();

  const int nt = K >> 5;
  int cur = 0;
  for (int t = 0; t < nt; ++t) {
    // issue next slab's loads BEFORE computing current -> latency overlap
    if (t+1 < nt) {
      const long long ko = (long long)(t+1)*32;
      #pragma unroll
      for (int j=0;j<NIA;++j){
        stage16(pAH + ko + (long long)j*16*lda, &AsH[cur^1][lofsA + j*512], lane);
        stage16(pAL + ko + (long long)j*16*lda, &AsL[cur^1][lofsA + j*512], lane);
      }
      #pragma unroll
      for (int j=0;j<NIB;++j){
        stage16(pBH + ko + (long long)j*16*ldb, &BsH[cur^1][lofsB + j*512], lane);
        stage16(pBL + ko + (long long)j*16*ldb, &BsL[cur^1][lofsB + j*512], lane);
      }
    }
    // compute current slab (staged & drained at previous barrier)
    short8 ah[FM], al[FM], bh[FN], bl[FN];
    #pragma unroll
    for (int mi=0; mi<FM; ++mi){
      const int off = (wr*WM + mi*16 + ln15)*32 + quad*8;
      ah[mi] = *(const short8*)&AsH[cur][off];
      al[mi] = *(const short8*)&AsL[cur][off];
    }
    #pragma unroll
    for (int ni=0; ni<FN; ++ni){
      const int off = (wc*WN + ni*16 + ln15)*32 + quad*8;
      bh[ni] = *(const short8*)&BsH[cur][off];
      bl[ni] = *(const short8*)&BsL[cur][off];
    }
    #pragma unroll
    for (int mi=0; mi<FM; ++mi)
      #pragma unroll
      for (int ni=0; ni<FN; ++ni){
        floatx4 c = acc[mi][ni];
        c = __builtin_amdgcn_mfma_f32_16x16x32_bf16(ah[mi], bh[ni], c, 0,0,0);
        c = __builtin_amdgcn_mfma_f32_16x16x32_bf16(ah[mi], bl[ni], c, 0,0,0);
        c = __builtin_amdgcn_mfma_f32_16x16x32_bf16(al[mi], bh[ni], c, 0,0,0);
        acc[mi][ni] = c;
      }
    __syncthreads();   // drains next-slab loads (residual) + protects buffers
    cur ^= 1;
  }

  #pragma unroll
  for (int mi=0; mi<FM; ++mi){
    const int rb = m0 + wr*WM + mi*16 + quad*4;
    #pragma unroll
    for (int ni=0; ni<FN; ++ni){
      const int col = n0 + wc*WN + ni*16 + ln15;
      const float bv = bias ? bias[col] : 0.f;
      #pragma unroll
      for (int r=0; r<4; ++r){
        const long long ci = (long long)(rb+r)*ldc + col;
        float v = acc[mi][ni][r]*scale + bv;
        if (act==1) v = gelu_f(v);
        if (resid) v += resid[ci];
        if (C) C[ci] = v;
        if (CH){ u16 h=f2bf(v); CH[ci]=h; CL[ci]=f2bf(v-bf2f(h)); }
        if (mirror) mirror[ci] = v;
      }
    }
  }
}

// WT H/L [n][k] = split(W[k][n]) ; W is K x N row-major f32
__global__ __launch_bounds__(256) void wtrans_split(
    const float* __restrict__ W, u16* __restrict__ WTH, u16* __restrict__ WTL,
    int K, int N)
{
  __shared__ float t[32][33];
  const int k0 = blockIdx.x*32, n0 = blockIdx.y*32;
  const int r = threadIdx.x >> 5, c = threadIdx.x & 31;
  #pragma unroll
  for (int p=0;p<4;++p) t[r+p*8][c] = W[(long long)(k0+r+p*8)*N + n0+c];
  __syncthreads();
  #pragma unroll
  for (int p=0;p<4;++p){
    const float v = t[c][r+p*8];
    split2(v, WTH, WTL, (long long)(n0+r+p*8)*K + k0+c);
  }
}

// wpermT H/L [o*2048 + r*512 + c] = split(conv_w[o*2048 + c*4 + r])
__global__ __launch_bounds__(256) void wpermT_split(
    const float* __restrict__ w, u16* __restrict__ H, u16* __restrict__ L)
{
  const int idx = blockIdx.x*256 + threadIdx.x; // < 1048576
  const int o = idx >> 11, rem = idx & 2047;
  const int r = rem >> 9, c = rem & 511;
  split2(w[(long long)o*2048 + c*4 + r], H, L, idx);
}

// vT H/L [(b*8+h)*73728 + d*1152 + t] = kvHL[b][t][512 + h*64 + d]
__global__ __launch_bounds__(256) void vtrans_hl(
    const u16* __restrict__ kvH, const u16* __restrict__ kvL,
    u16* __restrict__ vTH, u16* __restrict__ vTL)
{
  const int z = blockIdx.y, t0 = blockIdx.x*64;
  const int b = z >> 3, h = z & 7;
  __shared__ u16 tH[64][72], tL[64][72];
  const int r = threadIdx.x >> 6, c = threadIdx.x & 63;
  #pragma unroll
  for (int p=0;p<16;++p){
    const int row = r + p*4;
    const long long off = (long long)b*1179648 + (long long)(t0+row)*1024 + 512 + h*64 + c;
    tH[row][c] = kvH[off];
    tL[row][c] = kvL[off];
  }
  __syncthreads();
  #pragma unroll
  for (int p=0;p<16;++p){
    const int d = r + p*4;
    const long long o = (long long)z*73728 + (long long)d*1152 + t0 + c;
    vTH[o] = tH[c][d];
    vTL[o] = tL[c][d];
  }
}

// cvT H/L [(b*8+h)*8192 + d*128 + t] = ckvHL[b][t][512 + h*64 + d]
__global__ __launch_bounds__(256) void cvtrans_hl(
    const u16* __restrict__ ckvH, const u16* __restrict__ ckvL,
    u16* __restrict__ cvTH, u16* __restrict__ cvTL)
{
  const int z = blockIdx.y, t0 = blockIdx.x*64;
  const int b = z >> 3, h = z & 7;
  __shared__ u16 tH[64][72], tL[64][72];
  const int r = threadIdx.x >> 6, c = threadIdx.x & 63;
  #pragma unroll
  for (int p=0;p<16;++p){
    const int row = r + p*4;
    const long long off = (long long)b*131072 + (long long)(t0+row)*1024 + 512 + h*64 + c;
    tH[row][c] = ckvH[off];
    tL[row][c] = ckvL[off];
  }
  __syncthreads();
  #pragma unroll
  for (int p=0;p<16;++p){
    const int d = r + p*4;
    const long long o = (long long)z*8192 + (long long)d*128 + t0 + c;
    cvTH[o] = tH[c][d];
    cvTL[o] = tL[c][d];
  }
}

// x[row, d] = embed[seq[row], d] + pe[t, d]
__global__ __launch_bounds__(256) void embed_kernel(
    const int* __restrict__ seq, const float* __restrict__ emb,
    float* __restrict__ x)
{
  const int row = blockIdx.x;
  const int t = row & 511;
  const long long tok = seq[row];
  #pragma unroll
  for (int p = 0; p < 2; ++p) {
    const int d = threadIdx.x + p*256;
    const int j2 = d & ~1;
    const float div = __expf((float)j2 * (-0.0179889460f)); // -ln(10000)/512
    const float ang = (float)t * div;
    const float pe = (d & 1) ? cosf(ang) : sinf(ang);
    x[(long long)row*512 + d] = emb[tok*512 + d] + pe;
  }
}

// LayerNorm -> H/L split output (+ optional f32 mirror for new_mems)
__global__ __launch_bounds__(256) void ln_kernel(
    const float* __restrict__ x, const float* __restrict__ g,
    const float* __restrict__ b, u16* __restrict__ outH, u16* __restrict__ outL,
    float* __restrict__ mirror)
{
  const long long base = (long long)blockIdx.x*512;
  const int tid = threadIdx.x;
  const float v0 = x[base+tid], v1 = x[base+tid+256];
  const float mean = blockReduceSum(v0+v1) * (1.f/512.f);
  const float d0 = v0-mean, d1 = v1-mean;
  const float var = blockReduceSum(d0*d0+d1*d1) * (1.f/512.f);
  const float rstd = rsqrtf(var + 1e-5f);
  const float o0 = d0*rstd*g[tid]     + b[tid];
  const float o1 = d1*rstd*g[tid+256] + b[tid+256];
  split2(o0, outH, outL, base+tid);
  split2(o1, outH, outL, base+tid+256);
  if (mirror) { mirror[base+tid] = o0; mirror[base+tid+256] = o1; }
}

// cm H/L: (b, 640, 512) = [cmems (128) | mems (512)] rows, split
__global__ __launch_bounds__(256) void build_cm_kernel(
    const float* __restrict__ cmems_i, const float* __restrict__ mems_i,
    u16* __restrict__ H, u16* __restrict__ L)
{
  const long long idx = (long long)blockIdx.x*256 + threadIdx.x; // < 2621440
  const int c = (int)(idx & 511);
  const long long rb = idx >> 9;
  const int r = (int)(rb % 640);
  const int b = (int)(rb / 640);
  float v;
  if (r < 128) v = cmems_i[(long long)b*65536 + (long long)r*512 + c];
  else         v = mems_i[(long long)b*262144 + (long long)(r-128)*512 + c];
  split2(v, H, L, idx);
}

// in-place row softmax on H/L pair, single-read/single-write via register row
// cache (MAXP = ceil(Wd/256)). Optional fused accumulation of probabilities
// into acc[(blockIdx.x & 511)*Wd + i] (attns sum over z-slices) via atomicAdd.
template<int MAXP>
__global__ __launch_bounds__(256) void softmax_hl(
    u16* __restrict__ H, u16* __restrict__ L, int Wd, float* __restrict__ acc)
{
  const long long base = (long long)blockIdx.x * Wd;
  float v[MAXP];
  float mx = -3.4e38f;
  #pragma unroll
  for (int p = 0; p < MAXP; ++p){
    const int i = threadIdx.x + p*256;
    v[p] = (i < Wd) ? bf2f(H[base+i]) + bf2f(L[base+i]) : -3.4e38f;
    mx = fmaxf(mx, v[p]);
  }
  mx = blockReduceMax(mx);
  float sum = 0.f;
  #pragma unroll
  for (int p = 0; p < MAXP; ++p){
    const int i = threadIdx.x + p*256;
    if (i < Wd){ v[p] = __expf(v[p] - mx); sum += v[p]; }
  }
  sum = blockReduceSum(sum);
  const float inv = 1.f/sum;
  float* arow = acc ? acc + (long long)(blockIdx.x & 511)*Wd : nullptr;
  #pragma unroll
  for (int p = 0; p < MAXP; ++p){
    const int i = threadIdx.x + p*256;
    if (i < Wd){
      const float e = v[p]*inv;
      split2(e, H, L, base+i);
      if (arow) atomicAdd(arow + i, e);
    }
  }
}

__global__ __launch_bounds__(256) void sqdiff_kernel(
    const float* __restrict__ a, const float* __restrict__ b, float* __restrict__ accum)
{
  const int idx0 = blockIdx.x*1024 + threadIdx.x;
  float s = 0.f;
  #pragma unroll
  for (int p = 0; p < 4; ++p) {
    const int idx = idx0 + p*256;
    const float d = a[idx]-b[idx];
    s += d*d;
  }
  s = blockReduceSum(s);
  if (threadIdx.x == 0) atomicAdd(accum, s);
}

__global__ __launch_bounds__(256) void attns_final_kernel(
    const float* __restrict__ asum, float* __restrict__ out)
{
  const int idx = blockIdx.x*256 + threadIdx.x;
  if (idx < 589824) out[idx] = asum[idx]*(1.f/256.f);
}

__global__ void aux_final_kernel(const float* __restrict__ aux, float* __restrict__ out)
{
  out[0] = aux[0] * (1.f/8388608.f);
  out[1] = 0.f;
}

extern "C" void kernel_launch(void* const* d_in, const int* in_sizes, int n_in,
                              void* d_out, int out_size, void* d_ws, size_t ws_size,
                              hipStream_t stream)
{
  const int*   seq    = (const int*)d_in[0];
  // d_in[1] = mask: all-True -> no-op
  const float* mems   = (const float*)d_in[2];
  const float* cmems  = (const float*)d_in[3];
  const float* embed  = (const float*)d_in[4];
  const float* ln1_g  = (const float*)d_in[5];
  const float* ln1_b  = (const float*)d_in[6];
  const float* Wq     = (const float*)d_in[7];
  const float* Wkv    = (const float*)d_in[8];
  const float* Wo     = (const float*)d_in[9];
  const float* bo     = (const float*)d_in[10];
  const float* conv_w = (const float*)d_in[11];
  const float* conv_b = (const float*)d_in[12];
  const float* ln2_g  = (const float*)d_in[13];
  const float* ln2_b  = (const float*)d_in[14];
  const float* W1     = (const float*)d_in[15];
  const float* b1     = (const float*)d_in[16];
  const float* W2     = (const float*)d_in[17];
  const float* b2     = (const float*)d_in[18];
  float* out = (float*)d_out;

  // ---- workspace map (byte offsets), total ~182.7 MB (proven budget 186.9)
  char* W8 = (char*)d_ws;
  float* x     = (float*)(W8 + 0);              // 8,388,608 B
  u16* xnH     = (u16*)(W8 + 8388608LL);        // 4,194,304
  u16* xnL     = (u16*)(W8 + 12582912LL);
  u16* qH      = (u16*)(W8 + 16777216LL);       // 4,194,304 ; xn2H alias
  u16* qL      = (u16*)(W8 + 20971520LL);
  u16* cmH     = (u16*)(W8 + 25165824LL);       // 5,242,880
  u16* cmL     = (u16*)(W8 + 30408704LL);
  u16* kvH     = (u16*)(W8 + 35651584LL);       // 18,874,368 ; ffnhH alias
  u16* kvL     = (u16*)(W8 + 54525952LL);
  u16* vTH     = (u16*)(W8 + 73400320LL);       // 9,437,184
  u16* vTL     = (u16*)(W8 + 82837504LL);
  u16* dotsH   = (u16*)(W8 + 92274688LL);       // 18,874,368
  u16* dotsL   = (u16*)(W8 + 111149056LL);
  u16* aoutH   = (u16*)(W8 + 130023424LL);      // 4,194,304
  u16* aoutL   = (u16*)(W8 + 134217728LL);
  u16* compH   = (u16*)(W8 + 138412032LL);      // 1,048,576
  u16* compL   = (u16*)(W8 + 139460608LL);
  u16* ckvH    = (u16*)(W8 + 140509184LL);      // 2,097,152
  u16* ckvL    = (u16*)(W8 + 142606336LL);
  u16* cvTH    = (u16*)(W8 + 144703488LL);      // 1,048,576
  u16* cvTL    = (u16*)(W8 + 145752064LL);
  u16* wpTH    = (u16*)(W8 + 146800640LL);      // 2,097,152
  u16* wpTL    = (u16*)(W8 + 148897792LL);
  u16* WqTH    = (u16*)(W8 + 150994944LL);      // 524,288 (per-layer)
  u16* WqTL    = (u16*)(W8 + 151519232LL);
  u16* WkvTH   = (u16*)(W8 + 152043520LL);      // 1,048,576
  u16* WkvTL   = (u16*)(W8 + 153092096LL);
  u16* WoTH    = (u16*)(W8 + 154140672LL);      // 524,288
  u16* WoTL    = (u16*)(W8 + 154664960LL);
  u16* W1TH    = (u16*)(W8 + 155189248LL);      // 2,097,152
  u16* W1TL    = (u16*)(W8 + 157286400LL);
  u16* W2TH    = (u16*)(W8 + 159383552LL);      // 2,097,152
  u16* W2TL    = (u16*)(W8 + 161480704LL);
  float* o1    = (float*)(W8 + 163577856LL);    // 8,388,608
  float* o2    = (float*)(W8 + 171966464LL);    // 8,388,608
  float* attns = (float*)(W8 + 180355072LL);    // 2,359,296
  float* aux   = (float*)(W8 + 182714368LL);    // 4
  u16* xn2H = qH;  u16* xn2L = qL;              // q dead before ln2
  u16* ffnhH = kvH; u16* ffnhL = kvL;           // kv dead after aux1

  hipMemsetAsync(attns, 0, 589824*sizeof(float), stream);
  hipMemsetAsync(aux, 0, sizeof(float), stream);

  embed_kernel<<<4096,256,0,stream>>>(seq, embed, x);

  for (int i = 0; i < 4; ++i) {
    const float* bo_i   = bo   + (long long)i*512;
    const float* cw_i   = conv_w + (long long)i*1048576;
    const float* cb_i   = conv_b + (long long)i*512;
    const float* b1_i   = b1   + (long long)i*2048;
    const float* b2_i   = b2   + (long long)i*512;
    const float* mems_i = mems + (long long)i*2097152;
    const float* cmems_i= cmems+ (long long)i*524288;
    float* out_mems_i   = out + 2097152LL  + (long long)i*2097152;
    float* out_cmems_i  = out + 10485760LL + (long long)i*524288;

    // per-layer weight split (N x K hi/lo)
    wtrans_split<<<dim3(16,16),256,0,stream>>>(Wq + (long long)i*262144,  WqTH, WqTL, 512, 512);
    wtrans_split<<<dim3(16,32),256,0,stream>>>(Wkv+ (long long)i*524288,  WkvTH,WkvTL,512, 1024);
    wtrans_split<<<dim3(16,16),256,0,stream>>>(Wo + (long long)i*262144,  WoTH, WoTL, 512, 512);
    wtrans_split<<<dim3(16,64),256,0,stream>>>(W1 + (long long)i*1048576, W1TH, W1TL, 512, 2048);
    wtrans_split<<<dim3(64,16),256,0,stream>>>(W2 + (long long)i*1048576, W2TH, W2TL, 2048,512);

    // xn = LN1(x) -> hi/lo + new_mems f32
    ln_kernel<<<4096,256,0,stream>>>(x, ln1_g+(long long)i*512, ln1_b+(long long)i*512, xnH, xnL, out_mems_i);
    // q = xn @ Wq  (hi/lo out) ; 512 blocks = 2/CU
    mgemm<64,64><<<dim3(8,64,1),256,0,stream>>>(
        xnH,xnL, WqTH,WqTL, nullptr, qH,qL, nullptr,nullptr,nullptr,
        512, 512,512,512, 0,0,0,0,0,0, 1, 1.f, 0);
    // cm = [cmems|mems] split; kv rows 0-639 from cm, rows 640-1151 from xn
    build_cm_kernel<<<10240,256,0,stream>>>(cmems_i, mems_i, cmH, cmL);
    mgemm<64,128><<<dim3(8,10,8),256,0,stream>>>(
        cmH,cmL, WkvTH,WkvTL, nullptr, kvH,kvL, nullptr,nullptr,nullptr,
        512, 512,512,1024, 0,327680, 0,0, 0,1179648, 8, 1.f, 0);
    mgemm<64,128><<<dim3(8,8,8),256,0,stream>>>(
        xnH,xnL, WkvTH,WkvTL, nullptr, kvH+655360,kvL+655360, nullptr,nullptr,nullptr,
        512, 512,512,1024, 0,262144, 0,0, 0,1179648, 8, 1.f, 0);
    // vT (b,h,64,1152) hi/lo
    vtrans_hl<<<dim3(18,64),256,0,stream>>>(kvH, kvL, vTH, vTL);
    // main attention, 4 chunks of 16 z; vT chunk stride = 16*73728 = 1,179,648
    for (int c = 0; c < 4; ++c) {
      mgemm<64,128><<<dim3(9,8,16),256,0,stream>>>(
          qH + (long long)c*524288, qL + (long long)c*524288,
          kvH + (long long)c*2359296, kvL + (long long)c*2359296,
          nullptr, dotsH, dotsL, nullptr,nullptr,nullptr,
          64, 512,1024,1152, 262144,64, 1179648,64, 4718592,589824, 8, 0.125f, 0);
      softmax_hl<5><<<8192,256,0,stream>>>(dotsH, dotsL, 1152, attns);
      mgemm<64,64><<<dim3(1,8,16),256,0,stream>>>(
          dotsH, dotsL, vTH + (long long)c*1179648, vTL + (long long)c*1179648,
          nullptr, aoutH + (long long)c*524288, aoutL + (long long)c*524288,
          nullptr,nullptr,nullptr,
          1152, 1152,1152,512, 4718592,589824, 589824,73728, 262144,64, 8, 1.f, 0);
    }
    // x = aout @ Wo + bo + x   (f32 residual chain) ; 512 blocks
    mgemm<64,64><<<dim3(8,64,1),256,0,stream>>>(
        aoutH,aoutL, WoTH,WoTL, x, nullptr,nullptr, bo_i, x, nullptr,
        512, 512,512,512, 0,0,0,0,0,0, 1, 1.f, 0);
    // compression: comp = mems(128x2048/b) @ wpermT + conv_b ; 128 blocks
    wpermT_split<<<4096,256,0,stream>>>(cw_i, wpTH, wpTL);
    mgemm<64,64><<<dim3(8,2,8),256,0,stream>>>(
        cmH+65536, cmL+65536, wpTH, wpTL, out_cmems_i, compH, compL, cb_i, nullptr, nullptr,
        2048, 2048,2048,512, 0,327680, 0,0, 0,65536, 8, 1.f, 0);
    // ckv = comp @ Wkv (hi/lo) ; 256 blocks
    mgemm<64,64><<<dim3(16,16,1),256,0,stream>>>(
        compH,compL, WkvTH,WkvTL, nullptr, ckvH,ckvL, nullptr,nullptr,nullptr,
        512, 512,512,1024, 0,0,0,0,0,0, 1, 1.f, 0);
    cvtrans_hl<<<dim3(2,64),256,0,stream>>>(ckvH, ckvL, cvTH, cvTL);
    // aux attn 1 (old-mem K/V), 4 chunks of 16 z ; dots 512 blocks
    for (int c = 0; c < 4; ++c) {
      mgemm<64,128><<<dim3(4,8,16),256,0,stream>>>(
          qH + (long long)c*524288, qL + (long long)c*524288,
          kvH + (long long)c*2359296 + 131072, kvL + (long long)c*2359296 + 131072,
          nullptr, dotsH, dotsL, nullptr,nullptr,nullptr,
          64, 512,1024,512, 262144,64, 1179648,64, 2097152,262144, 8, 0.125f, 0);
      softmax_hl<2><<<8192,256,0,stream>>>(dotsH, dotsL, 512, nullptr);
      mgemm<64,64><<<dim3(1,8,16),256,0,stream>>>(
          dotsH, dotsL, vTH + (long long)c*1179648 + 128, vTL + (long long)c*1179648 + 128,
          o1 + (long long)c*524288, nullptr,nullptr, nullptr,nullptr,nullptr,
          512, 512,1152,64, 2097152,262144, 589824,73728, 262144,32768, 8, 1.f, 0);
    }
    // aux attn 2 (compressed K/V), all 64 z ; 512 blocks
    mgemm<64,128><<<dim3(1,8,64),256,0,stream>>>(
        qH,qL, ckvH,ckvL, nullptr, dotsH, dotsL, nullptr,nullptr,nullptr,
        64, 512,1024,128, 262144,64, 131072,64, 524288,65536, 8, 0.125f, 0);
    softmax_hl<1><<<32768,256,0,stream>>>(dotsH, dotsL, 128, nullptr);
    mgemm<64,64><<<dim3(1,8,64),256,0,stream>>>(
        dotsH, dotsL, cvTH, cvTL, o2, nullptr,nullptr, nullptr,nullptr,nullptr,
        128, 128,128,64, 524288,65536, 65536,8192, 262144,32768, 8, 1.f, 0);
    sqdiff_kernel<<<2048,256,0,stream>>>(o1, o2, aux);
    // FFN
    ln_kernel<<<4096,256,0,stream>>>(x, ln2_g+(long long)i*512, ln2_b+(long long)i*512, xn2H, xn2L, nullptr);
    mgemm<64,128><<<dim3(16,64,1),256,0,stream>>>(
        xn2H,xn2L, W1TH,W1TL, nullptr, ffnhH,ffnhL, b1_i, nullptr, nullptr,
        512, 512,512,2048, 0,0,0,0,0,0, 1, 1.f, 1);
    mgemm<64,64><<<dim3(8,64,1),256,0,stream>>>(
        ffnhH,ffnhL, W2TH,W2TL, x, nullptr,nullptr, b2_i, x, (i==3) ? out : nullptr,
        2048, 2048,2048,512, 0,0,0,0,0,0, 1, 1.f, 0);
  }

  attns_final_kernel<<<2304,256,0,stream>>>(attns, out + 12582914LL);
  aux_final_kernel<<<1,1,0,stream>>>(aux, out + 12582912LL);
}

// Round 5
// 3572.681 us; speedup vs baseline: 1.0358x; 1.0358x over previous
//
#include <hip/hip_runtime.h>
#include <hip/hip_bf16.h>

#define DEV __device__ __forceinline__

typedef unsigned short u16;
typedef __attribute__((ext_vector_type(8))) short short8;
typedef __attribute__((ext_vector_type(4))) float floatx4;

DEV float gelu_f(float x){ return 0.5f*x*(1.0f+erff(x*0.7071067811865476f)); }

DEV u16 f2bf(float x){
  union { __hip_bfloat16 h; u16 u; } cv;
  cv.h = __float2bfloat16(x);
  return cv.u;
}
DEV float bf2f(u16 u){
  union { unsigned int u32; float f; } cv;
  cv.u32 = ((unsigned int)u) << 16;
  return cv.f;
}
DEV void split2(float v, u16* H, u16* L, long long i){
  u16 h = f2bf(v); H[i] = h; L[i] = f2bf(v - bf2f(h));
}

// async global->LDS 16B per lane; lds dest = wave-uniform base + lane*16
DEV void stage16(const u16* g, u16* lwave, int lane){
#if __has_builtin(__builtin_amdgcn_global_load_lds)
  __builtin_amdgcn_global_load_lds((const __attribute__((address_space(1))) void*)g,
                                   (__attribute__((address_space(3))) void*)lwave, 16, 0, 0);
#else
  *(short8*)(lwave + (long long)lane*8) = *(const short8*)g;
#endif
}

DEV float blockReduceSum(float v){
  __shared__ float red[4];
  int lane = threadIdx.x & 63, wid = threadIdx.x >> 6;
  #pragma unroll
  for (int off=32; off>0; off>>=1) v += __shfl_down(v, off, 64);
  __syncthreads();
  if (lane==0) red[wid]=v;
  __syncthreads();
  return red[0]+red[1]+red[2]+red[3];
}
DEV float blockReduceMax(float v){
  __shared__ float redm[4];
  int lane = threadIdx.x & 63, wid = threadIdx.x >> 6;
  #pragma unroll
  for (int off=32; off>0; off>>=1) v = fmaxf(v, __shfl_down(v, off, 64));
  __syncthreads();
  if (lane==0) redm[wid]=v;
  __syncthreads();
  return fmaxf(fmaxf(redm[0],redm[1]),fmaxf(redm[2],redm[3]));
}

// ---------------------------------------------------------------------------
// bf16x3 MFMA GEMM on pre-split hi/lo operands.
// A: M x K rows (lda), B: N x K rows (ldb), both as separate H/L u16 arrays.
// K-step 64 = two 32-el LDS panels staged back-to-back, ONE barrier pair per
// 64 K-elements (round-3 verified structure).
// Epilogue: v = scale*acc + bias -> act -> +resid. f32 C/mirror written
// direct; CH/CL staged through a block-wide LDS image (reusing the staging
// LDS) and streamed out as full 128B-aligned lines -> kills the
// write-allocate RMW over-fetch (FETCH_SIZE ~= write volume evidence, r3).
// Two-level batch via blockIdx.z = b1*B2+b2.
// Call sites guarantee M%BM==0, N%BN==0, K%64==0.
// ---------------------------------------------------------------------------
template<int BM, int BN>
__global__ __launch_bounds__(256) void mgemm(
    const u16* __restrict__ AH, const u16* __restrict__ AL,
    const u16* __restrict__ BH, const u16* __restrict__ BL,
    float* __restrict__ C, u16* __restrict__ CH, u16* __restrict__ CL,
    const float* __restrict__ bias, const float* __restrict__ resid,
    float* __restrict__ mirror,
    int K, int lda, int ldb, int ldc,
    long long sA1, long long sA2, long long sB1, long long sB2,
    long long sC1, long long sC2, int B2, float scale, int act)
{
  const int b1 = blockIdx.z / B2, b2 = blockIdx.z % B2;
  const long long aOff = b1*sA1 + b2*sA2;
  const long long bOff = b1*sB1 + b2*sB2;
  const long long cOff = b1*sC1 + b2*sC2;
  AH += aOff; AL += aOff; BH += bOff; BL += bOff;
  if (C) C += cOff;
  if (CH){ CH += cOff; CL += cOff; }
  if (resid) resid += cOff;
  if (mirror) mirror += cOff;

  const int m0 = blockIdx.y*BM, n0 = blockIdx.x*BN;
  const int tid = threadIdx.x, lane = tid & 63, wid = tid >> 6;
  const int ln15 = lane & 15, quad = lane >> 4;
  constexpr int WM = BM/2, WN = BN/2, FM = WM/16, FN = WN/16;
  constexpr int RWA = BM/4, RWB = BN/4;   // staging rows per wave (per panel)
  constexpr int NIA = BM/64, NIB = BN/64; // staging insts per wave per stream per panel
  const int wr = wid >> 1, wc = wid & 1;

  // LDS union: staging (2 panels x A/B x H/L) vs epilogue CH/CL image
  constexpr int STAGE_U16 = 128*BM + 128*BN;  // 2*BM*32*2 + 2*BN*32*2
  constexpr int EPI_U16   = 2*BM*BN;
  constexpr int SMEM_U16  = STAGE_U16 > EPI_U16 ? STAGE_U16 : EPI_U16;
  __shared__ u16 smem[SMEM_U16];
  u16* AsH = smem;                 // [2*BM*32]
  u16* AsL = AsH + 2*BM*32;
  u16* BsH = AsL + 2*BM*32;        // [2*BN*32]
  u16* BsL = BsH + 2*BN*32;

  floatx4 acc[FM][FN];
  #pragma unroll
  for (int a=0;a<FM;++a)
    #pragma unroll
    for (int b=0;b<FN;++b) acc[a][b] = (floatx4){0.f,0.f,0.f,0.f};

  // per-lane global staging pointers; LDS slot for lane = wavebase + lane*16B
  const int rA = wid*RWA + (lane >> 2), cA = (lane & 3)*8;
  const int rB = wid*RWB + (lane >> 2), cB = (lane & 3)*8;
  const u16* pAH = AH + (long long)(m0 + rA)*lda + cA;
  const u16* pAL = AL + (long long)(m0 + rA)*lda + cA;
  const u16* pBH = BH + (long long)(n0 + rB)*ldb + cB;
  const u16* pBL = BL + (long long)(n0 + rB)*ldb + cB;
  u16* lAH = AsH + wid*RWA*32;
  u16* lAL = AsL + wid*RWA*32;
  u16* lBH = BsH + wid*RWB*32;
  u16* lBL = BsL + wid*RWB*32;

  for (int k0 = 0; k0 < K; k0 += 64) {
    #pragma unroll
    for (int s=0;s<2;++s){
      #pragma unroll
      for (int j=0;j<NIA;++j){
        stage16(pAH + s*32 + (long long)j*16*lda, lAH + s*BM*32 + j*512, lane);
        stage16(pAL + s*32 + (long long)j*16*lda, lAL + s*BM*32 + j*512, lane);
      }
      #pragma unroll
      for (int j=0;j<NIB;++j){
        stage16(pBH + s*32 + (long long)j*16*ldb, lBH + s*BN*32 + j*512, lane);
        stage16(pBL + s*32 + (long long)j*16*ldb, lBL + s*BN*32 + j*512, lane);
      }
    }
    __syncthreads();   // drains vmcnt before barrier -> tiles visible

    short8 ah[FM][2], al[FM][2], bh[FN][2], bl[FN][2];
    #pragma unroll
    for (int mi=0; mi<FM; ++mi)
      #pragma unroll
      for (int s=0;s<2;++s){
        const int off = s*BM*32 + (wr*WM + mi*16 + ln15)*32 + quad*8;
        ah[mi][s] = *(const short8*)&AsH[off];
        al[mi][s] = *(const short8*)&AsL[off];
      }
    #pragma unroll
    for (int ni=0; ni<FN; ++ni)
      #pragma unroll
      for (int s=0;s<2;++s){
        const int off = s*BN*32 + (wc*WN + ni*16 + ln15)*32 + quad*8;
        bh[ni][s] = *(const short8*)&BsH[off];
        bl[ni][s] = *(const short8*)&BsL[off];
      }
    #pragma unroll
    for (int mi=0; mi<FM; ++mi)
      #pragma unroll
      for (int ni=0; ni<FN; ++ni){
        floatx4 c = acc[mi][ni];
        #pragma unroll
        for (int s=0;s<2;++s){
          c = __builtin_amdgcn_mfma_f32_16x16x32_bf16(ah[mi][s], bh[ni][s], c, 0,0,0);
          c = __builtin_amdgcn_mfma_f32_16x16x32_bf16(ah[mi][s], bl[ni][s], c, 0,0,0);
          c = __builtin_amdgcn_mfma_f32_16x16x32_bf16(al[mi][s], bh[ni][s], c, 0,0,0);
        }
        acc[mi][ni] = c;
      }
    __syncthreads();
    pAH += 64; pAL += 64; pBH += 64; pBL += 64;
  }

  // ---- epilogue ----
  // staging LDS is dead after the loop's final barrier; reuse for CH/CL image
  u16* eH = smem;            // [BM*BN]
  u16* eL = smem + BM*BN;    // [BM*BN]
  #pragma unroll
  for (int mi=0; mi<FM; ++mi){
    const int rbl = wr*WM + mi*16 + quad*4;     // local row base in tile
    #pragma unroll
    for (int ni=0; ni<FN; ++ni){
      const int coll = wc*WN + ni*16 + ln15;    // local col in tile
      const int colg = n0 + coll;
      const float bv = bias ? bias[colg] : 0.f;
      #pragma unroll
      for (int r=0; r<4; ++r){
        float v = acc[mi][ni][r]*scale + bv;
        if (act==1) v = gelu_f(v);
        const long long ci = (long long)(m0+rbl+r)*ldc + colg;
        if (resid) v += resid[ci];
        if (C) C[ci] = v;
        if (mirror) mirror[ci] = v;
        if (CH){
          const int li = (rbl+r)*BN + coll;
          u16 h = f2bf(v);
          eH[li] = h;
          eL[li] = f2bf(v - bf2f(h));
        }
      }
    }
  }
  if (CH){
    __syncthreads();  // all fragments deposited
    constexpr int PASSES = (BM*BN)/(256*8);  // 16B per thread per pass
    #pragma unroll
    for (int p=0;p<PASSES;++p){
      const int idx = (p*256 + tid)*8;       // u16 index, 16B-aligned
      const int rr = idx / BN, cc = idx % BN;
      const long long gi = (long long)(m0+rr)*ldc + n0+cc;
      *(short8*)&CH[gi] = *(const short8*)&eH[idx];
      *(short8*)&CL[gi] = *(const short8*)&eL[idx];
    }
  }
}

// WT H/L [n][k] = split(W[k][n]) ; W is K x N row-major f32
__global__ __launch_bounds__(256) void wtrans_split(
    const float* __restrict__ W, u16* __restrict__ WTH, u16* __restrict__ WTL,
    int K, int N)
{
  __shared__ float t[32][33];
  const int k0 = blockIdx.x*32, n0 = blockIdx.y*32;
  const int r = threadIdx.x >> 5, c = threadIdx.x & 31;
  #pragma unroll
  for (int p=0;p<4;++p) t[r+p*8][c] = W[(long long)(k0+r+p*8)*N + n0+c];
  __syncthreads();
  #pragma unroll
  for (int p=0;p<4;++p){
    const float v = t[c][r+p*8];
    split2(v, WTH, WTL, (long long)(n0+r+p*8)*K + k0+c);
  }
}

// wpermT H/L [o*2048 + r*512 + c] = split(conv_w[o*2048 + c*4 + r])
__global__ __launch_bounds__(256) void wpermT_split(
    const float* __restrict__ w, u16* __restrict__ H, u16* __restrict__ L)
{
  const int idx = blockIdx.x*256 + threadIdx.x; // < 1048576
  const int o = idx >> 11, rem = idx & 2047;
  const int r = rem >> 9, c = rem & 511;
  split2(w[(long long)o*2048 + c*4 + r], H, L, idx);
}

// vT H/L [(b*8+h)*73728 + d*1152 + t] = kvHL[b][t][512 + h*64 + d]
__global__ __launch_bounds__(256) void vtrans_hl(
    const u16* __restrict__ kvH, const u16* __restrict__ kvL,
    u16* __restrict__ vTH, u16* __restrict__ vTL)
{
  const int z = blockIdx.y, t0 = blockIdx.x*64;
  const int b = z >> 3, h = z & 7;
  __shared__ u16 tH[64][72], tL[64][72];
  const int r = threadIdx.x >> 6, c = threadIdx.x & 63;
  #pragma unroll
  for (int p=0;p<16;++p){
    const int row = r + p*4;
    const long long off = (long long)b*1179648 + (long long)(t0+row)*1024 + 512 + h*64 + c;
    tH[row][c] = kvH[off];
    tL[row][c] = kvL[off];
  }
  __syncthreads();
  #pragma unroll
  for (int p=0;p<16;++p){
    const int d = r + p*4;
    const long long o = (long long)z*73728 + (long long)d*1152 + t0 + c;
    vTH[o] = tH[c][d];
    vTL[o] = tL[c][d];
  }
}

// cvT H/L [(b*8+h)*8192 + d*128 + t] = ckvHL[b][t][512 + h*64 + d]
__global__ __launch_bounds__(256) void cvtrans_hl(
    const u16* __restrict__ ckvH, const u16* __restrict__ ckvL,
    u16* __restrict__ cvTH, u16* __restrict__ cvTL)
{
  const int z = blockIdx.y, t0 = blockIdx.x*64;
  const int b = z >> 3, h = z & 7;
  __shared__ u16 tH[64][72], tL[64][72];
  const int r = threadIdx.x >> 6, c = threadIdx.x & 63;
  #pragma unroll
  for (int p=0;p<16;++p){
    const int row = r + p*4;
    const long long off = (long long)b*131072 + (long long)(t0+row)*1024 + 512 + h*64 + c;
    tH[row][c] = ckvH[off];
    tL[row][c] = ckvL[off];
  }
  __syncthreads();
  #pragma unroll
  for (int p=0;p<16;++p){
    const int d = r + p*4;
    const long long o = (long long)z*8192 + (long long)d*128 + t0 + c;
    cvTH[o] = tH[c][d];
    cvTL[o] = tL[c][d];
  }
}

// x[row, d] = embed[seq[row], d] + pe[t, d]
__global__ __launch_bounds__(256) void embed_kernel(
    const int* __restrict__ seq, const float* __restrict__ emb,
    float* __restrict__ x)
{
  const int row = blockIdx.x;
  const int t = row & 511;
  const long long tok = seq[row];
  #pragma unroll
  for (int p = 0; p < 2; ++p) {
    const int d = threadIdx.x + p*256;
    const int j2 = d & ~1;
    const float div = __expf((float)j2 * (-0.0179889460f)); // -ln(10000)/512
    const float ang = (float)t * div;
    const float pe = (d & 1) ? cosf(ang) : sinf(ang);
    x[(long long)row*512 + d] = emb[tok*512 + d] + pe;
  }
}

// LayerNorm -> H/L split output (+ optional f32 mirror for new_mems)
__global__ __launch_bounds__(256) void ln_kernel(
    const float* __restrict__ x, const float* __restrict__ g,
    const float* __restrict__ b, u16* __restrict__ outH, u16* __restrict__ outL,
    float* __restrict__ mirror)
{
  const long long base = (long long)blockIdx.x*512;
  const int tid = threadIdx.x;
  const float v0 = x[base+tid], v1 = x[base+tid+256];
  const float mean = blockReduceSum(v0+v1) * (1.f/512.f);
  const float d0 = v0-mean, d1 = v1-mean;
  const float var = blockReduceSum(d0*d0+d1*d1) * (1.f/512.f);
  const float rstd = rsqrtf(var + 1e-5f);
  const float o0 = d0*rstd*g[tid]     + b[tid];
  const float o1 = d1*rstd*g[tid+256] + b[tid+256];
  split2(o0, outH, outL, base+tid);
  split2(o1, outH, outL, base+tid+256);
  if (mirror) { mirror[base+tid] = o0; mirror[base+tid+256] = o1; }
}

// cm H/L: (b, 640, 512) = [cmems (128) | mems (512)] rows, split
__global__ __launch_bounds__(256) void build_cm_kernel(
    const float* __restrict__ cmems_i, const float* __restrict__ mems_i,
    u16* __restrict__ H, u16* __restrict__ L)
{
  const long long idx = (long long)blockIdx.x*256 + threadIdx.x; // < 2621440
  const int c = (int)(idx & 511);
  const long long rb = idx >> 9;
  const int r = (int)(rb % 640);
  const int b = (int)(rb / 640);
  float v;
  if (r < 128) v = cmems_i[(long long)b*65536 + (long long)r*512 + c];
  else         v = mems_i[(long long)b*262144 + (long long)(r-128)*512 + c];
  split2(v, H, L, idx);
}

// in-place row softmax on H/L pair, single-read/single-write via register row
// cache (MAXP = ceil(Wd/256)). Optional fused accumulation of probabilities
// into acc[(blockIdx.x & 511)*Wd + i] (attns sum over z-slices) via atomicAdd.
template<int MAXP>
__global__ __launch_bounds__(256) void softmax_hl(
    u16* __restrict__ H, u16* __restrict__ L, int Wd, float* __restrict__ acc)
{
  const long long base = (long long)blockIdx.x * Wd;
  float v[MAXP];
  float mx = -3.4e38f;
  #pragma unroll
  for (int p = 0; p < MAXP; ++p){
    const int i = threadIdx.x + p*256;
    v[p] = (i < Wd) ? bf2f(H[base+i]) + bf2f(L[base+i]) : -3.4e38f;
    mx = fmaxf(mx, v[p]);
  }
  mx = blockReduceMax(mx);
  float sum = 0.f;
  #pragma unroll
  for (int p = 0; p < MAXP; ++p){
    const int i = threadIdx.x + p*256;
    if (i < Wd){ v[p] = __expf(v[p] - mx); sum += v[p]; }
  }
  sum = blockReduceSum(sum);
  const float inv = 1.f/sum;
  float* arow = acc ? acc + (long long)(blockIdx.x & 511)*Wd : nullptr;
  #pragma unroll
  for (int p = 0; p < MAXP; ++p){
    const int i = threadIdx.x + p*256;
    if (i < Wd){
      const float e = v[p]*inv;
      split2(e, H, L, base+i);
      if (arow) atomicAdd(arow + i, e);
    }
  }
}

__global__ __launch_bounds__(256) void sqdiff_kernel(
    const float* __restrict__ a, const float* __restrict__ b, float* __restrict__ accum)
{
  const int idx0 = blockIdx.x*1024 + threadIdx.x;
  float s = 0.f;
  #pragma unroll
  for (int p = 0; p < 4; ++p) {
    const int idx = idx0 + p*256;
    const float d = a[idx]-b[idx];
    s += d*d;
  }
  s = blockReduceSum(s);
  if (threadIdx.x == 0) atomicAdd(accum, s);
}

__global__ __launch_bounds__(256) void attns_final_kernel(
    const float* __restrict__ asum, float* __restrict__ out)
{
  const int idx = blockIdx.x*256 + threadIdx.x;
  if (idx < 589824) out[idx] = asum[idx]*(1.f/256.f);
}

__global__ void aux_final_kernel(const float* __restrict__ aux, float* __restrict__ out)
{
  out[0] = aux[0] * (1.f/8388608.f);
  out[1] = 0.f;
}

extern "C" void kernel_launch(void* const* d_in, const int* in_sizes, int n_in,
                              void* d_out, int out_size, void* d_ws, size_t ws_size,
                              hipStream_t stream)
{
  const int*   seq    = (const int*)d_in[0];
  // d_in[1] = mask: all-True -> no-op
  const float* mems   = (const float*)d_in[2];
  const float* cmems  = (const float*)d_in[3];
  const float* embed  = (const float*)d_in[4];
  const float* ln1_g  = (const float*)d_in[5];
  const float* ln1_b  = (const float*)d_in[6];
  const float* Wq     = (const float*)d_in[7];
  const float* Wkv    = (const float*)d_in[8];
  const float* Wo     = (const float*)d_in[9];
  const float* bo     = (const float*)d_in[10];
  const float* conv_w = (const float*)d_in[11];
  const float* conv_b = (const float*)d_in[12];
  const float* ln2_g  = (const float*)d_in[13];
  const float* ln2_b  = (const float*)d_in[14];
  const float* W1     = (const float*)d_in[15];
  const float* b1     = (const float*)d_in[16];
  const float* W2     = (const float*)d_in[17];
  const float* b2     = (const float*)d_in[18];
  float* out = (float*)d_out;

  // ---- workspace map (byte offsets), total ~182.7 MB (proven budget 186.9)
  char* W8 = (char*)d_ws;
  float* x     = (float*)(W8 + 0);              // 8,388,608 B
  u16* xnH     = (u16*)(W8 + 8388608LL);        // 4,194,304
  u16* xnL     = (u16*)(W8 + 12582912LL);
  u16* qH      = (u16*)(W8 + 16777216LL);       // 4,194,304 ; xn2H alias
  u16* qL      = (u16*)(W8 + 20971520LL);
  u16* cmH     = (u16*)(W8 + 25165824LL);       // 5,242,880
  u16* cmL     = (u16*)(W8 + 30408704LL);
  u16* kvH     = (u16*)(W8 + 35651584LL);       // 18,874,368 ; ffnhH alias
  u16* kvL     = (u16*)(W8 + 54525952LL);
  u16* vTH     = (u16*)(W8 + 73400320LL);       // 9,437,184
  u16* vTL     = (u16*)(W8 + 82837504LL);
  u16* dotsH   = (u16*)(W8 + 92274688LL);       // 18,874,368
  u16* dotsL   = (u16*)(W8 + 111149056LL);
  u16* aoutH   = (u16*)(W8 + 130023424LL);      // 4,194,304
  u16* aoutL   = (u16*)(W8 + 134217728LL);
  u16* compH   = (u16*)(W8 + 138412032LL);      // 1,048,576
  u16* compL   = (u16*)(W8 + 139460608LL);
  u16* ckvH    = (u16*)(W8 + 140509184LL);      // 2,097,152
  u16* ckvL    = (u16*)(W8 + 142606336LL);
  u16* cvTH    = (u16*)(W8 + 144703488LL);      // 1,048,576
  u16* cvTL    = (u16*)(W8 + 145752064LL);
  u16* wpTH    = (u16*)(W8 + 146800640LL);      // 2,097,152
  u16* wpTL    = (u16*)(W8 + 148897792LL);
  u16* WqTH    = (u16*)(W8 + 150994944LL);      // 524,288 (per-layer)
  u16* WqTL    = (u16*)(W8 + 151519232LL);
  u16* WkvTH   = (u16*)(W8 + 152043520LL);      // 1,048,576
  u16* WkvTL   = (u16*)(W8 + 153092096LL);
  u16* WoTH    = (u16*)(W8 + 154140672LL);      // 524,288
  u16* WoTL    = (u16*)(W8 + 154664960LL);
  u16* W1TH    = (u16*)(W8 + 155189248LL);      // 2,097,152
  u16* W1TL    = (u16*)(W8 + 157286400LL);
  u16* W2TH    = (u16*)(W8 + 159383552LL);      // 2,097,152
  u16* W2TL    = (u16*)(W8 + 161480704LL);
  float* o1    = (float*)(W8 + 163577856LL);    // 8,388,608
  float* o2    = (float*)(W8 + 171966464LL);    // 8,388,608
  float* attns = (float*)(W8 + 180355072LL);    // 2,359,296
  float* aux   = (float*)(W8 + 182714368LL);    // 4
  u16* xn2H = qH;  u16* xn2L = qL;              // q dead before ln2
  u16* ffnhH = kvH; u16* ffnhL = kvL;           // kv dead after aux1

  hipMemsetAsync(attns, 0, 589824*sizeof(float), stream);
  hipMemsetAsync(aux, 0, sizeof(float), stream);

  embed_kernel<<<4096,256,0,stream>>>(seq, embed, x);

  for (int i = 0; i < 4; ++i) {
    const float* bo_i   = bo   + (long long)i*512;
    const float* cw_i   = conv_w + (long long)i*1048576;
    const float* cb_i   = conv_b + (long long)i*512;
    const float* b1_i   = b1   + (long long)i*2048;
    const float* b2_i   = b2   + (long long)i*512;
    const float* mems_i = mems + (long long)i*2097152;
    const float* cmems_i= cmems+ (long long)i*524288;
    float* out_mems_i   = out + 2097152LL  + (long long)i*2097152;
    float* out_cmems_i  = out + 10485760LL + (long long)i*524288;

    // per-layer weight split (N x K hi/lo)
    wtrans_split<<<dim3(16,16),256,0,stream>>>(Wq + (long long)i*262144,  WqTH, WqTL, 512, 512);
    wtrans_split<<<dim3(16,32),256,0,stream>>>(Wkv+ (long long)i*524288,  WkvTH,WkvTL,512, 1024);
    wtrans_split<<<dim3(16,16),256,0,stream>>>(Wo + (long long)i*262144,  WoTH, WoTL, 512, 512);
    wtrans_split<<<dim3(16,64),256,0,stream>>>(W1 + (long long)i*1048576, W1TH, W1TL, 512, 2048);
    wtrans_split<<<dim3(64,16),256,0,stream>>>(W2 + (long long)i*1048576, W2TH, W2TL, 2048,512);

    // xn = LN1(x) -> hi/lo + new_mems f32
    ln_kernel<<<4096,256,0,stream>>>(x, ln1_g+(long long)i*512, ln1_b+(long long)i*512, xnH, xnL, out_mems_i);
    // q = xn @ Wq  (hi/lo out) ; 512 blocks = 2/CU
    mgemm<64,64><<<dim3(8,64,1),256,0,stream>>>(
        xnH,xnL, WqTH,WqTL, nullptr, qH,qL, nullptr,nullptr,nullptr,
        512, 512,512,512, 0,0,0,0,0,0, 1, 1.f, 0);
    // cm = [cmems|mems] split; kv rows 0-639 from cm, rows 640-1151 from xn
    build_cm_kernel<<<10240,256,0,stream>>>(cmems_i, mems_i, cmH, cmL);
    mgemm<64,128><<<dim3(8,10,8),256,0,stream>>>(
        cmH,cmL, WkvTH,WkvTL, nullptr, kvH,kvL, nullptr,nullptr,nullptr,
        512, 512,512,1024, 0,327680, 0,0, 0,1179648, 8, 1.f, 0);
    mgemm<64,128><<<dim3(8,8,8),256,0,stream>>>(
        xnH,xnL, WkvTH,WkvTL, nullptr, kvH+655360,kvL+655360, nullptr,nullptr,nullptr,
        512, 512,512,1024, 0,262144, 0,0, 0,1179648, 8, 1.f, 0);
    // vT (b,h,64,1152) hi/lo
    vtrans_hl<<<dim3(18,64),256,0,stream>>>(kvH, kvL, vTH, vTL);
    // main attention, 4 chunks of 16 z; vT chunk stride = 16*73728 = 1,179,648
    for (int c = 0; c < 4; ++c) {
      mgemm<64,128><<<dim3(9,8,16),256,0,stream>>>(
          qH + (long long)c*524288, qL + (long long)c*524288,
          kvH + (long long)c*2359296, kvL + (long long)c*2359296,
          nullptr, dotsH, dotsL, nullptr,nullptr,nullptr,
          64, 512,1024,1152, 262144,64, 1179648,64, 4718592,589824, 8, 0.125f, 0);
      softmax_hl<5><<<8192,256,0,stream>>>(dotsH, dotsL, 1152, attns);
      mgemm<64,64><<<dim3(1,8,16),256,0,stream>>>(
          dotsH, dotsL, vTH + (long long)c*1179648, vTL + (long long)c*1179648,
          nullptr, aoutH + (long long)c*524288, aoutL + (long long)c*524288,
          nullptr,nullptr,nullptr,
          1152, 1152,1152,512, 4718592,589824, 589824,73728, 262144,64, 8, 1.f, 0);
    }
    // x = aout @ Wo + bo + x   (f32 residual chain) ; 512 blocks
    mgemm<64,64><<<dim3(8,64,1),256,0,stream>>>(
        aoutH,aoutL, WoTH,WoTL, x, nullptr,nullptr, bo_i, x, nullptr,
        512, 512,512,512, 0,0,0,0,0,0, 1, 1.f, 0);
    // compression: comp = mems(128x2048/b) @ wpermT + conv_b ; 128 blocks
    wpermT_split<<<4096,256,0,stream>>>(cw_i, wpTH, wpTL);
    mgemm<64,64><<<dim3(8,2,8),256,0,stream>>>(
        cmH+65536, cmL+65536, wpTH, wpTL, out_cmems_i, compH, compL, cb_i, nullptr, nullptr,
        2048, 2048,2048,512, 0,327680, 0,0, 0,65536, 8, 1.f, 0);
    // ckv = comp @ Wkv (hi/lo) ; 256 blocks
    mgemm<64,64><<<dim3(16,16,1),256,0,stream>>>(
        compH,compL, WkvTH,WkvTL, nullptr, ckvH,ckvL, nullptr,nullptr,nullptr,
        512, 512,512,1024, 0,0,0,0,0,0, 1, 1.f, 0);
    cvtrans_hl<<<dim3(2,64),256,0,stream>>>(ckvH, ckvL, cvTH, cvTL);
    // aux attn 1 (old-mem K/V), 4 chunks of 16 z ; dots 512 blocks
    for (int c = 0; c < 4; ++c) {
      mgemm<64,128><<<dim3(4,8,16),256,0,stream>>>(
          qH + (long long)c*524288, qL + (long long)c*524288,
          kvH + (long long)c*2359296 + 131072, kvL + (long long)c*2359296 + 131072,
          nullptr, dotsH, dotsL, nullptr,nullptr,nullptr,
          64, 512,1024,512, 262144,64, 1179648,64, 2097152,262144, 8, 0.125f, 0);
      softmax_hl<2><<<8192,256,0,stream>>>(dotsH, dotsL, 512, nullptr);
      mgemm<64,64><<<dim3(1,8,16),256,0,stream>>>(
          dotsH, dotsL, vTH + (long long)c*1179648 + 128, vTL + (long long)c*1179648 + 128,
          o1 + (long long)c*524288, nullptr,nullptr, nullptr,nullptr,nullptr,
          512, 512,1152,64, 2097152,262144, 589824,73728, 262144,32768, 8, 1.f, 0);
    }
    // aux attn 2 (compressed K/V), all 64 z ; 512 blocks
    mgemm<64,128><<<dim3(1,8,64),256,0,stream>>>(
        qH,qL, ckvH,ckvL, nullptr, dotsH, dotsL, nullptr,nullptr,nullptr,
        64, 512,1024,128, 262144,64, 131072,64, 524288,65536, 8, 0.125f, 0);
    softmax_hl<1><<<32768,256,0,stream>>>(dotsH, dotsL, 128, nullptr);
    mgemm<64,64><<<dim3(1,8,64),256,0,stream>>>(
        dotsH, dotsL, cvTH, cvTL, o2, nullptr,nullptr, nullptr,nullptr,nullptr,
        128, 128,128,64, 524288,65536, 65536,8192, 262144,32768, 8, 1.f, 0);
    sqdiff_kernel<<<2048,256,0,stream>>>(o1, o2, aux);
    // FFN
    ln_kernel<<<4096,256,0,stream>>>(x, ln2_g+(long long)i*512, ln2_b+(long long)i*512, xn2H, xn2L, nullptr);
    mgemm<64,128><<<dim3(16,64,1),256,0,stream>>>(
        xn2H,xn2L, W1TH,W1TL, nullptr, ffnhH,ffnhL, b1_i, nullptr, nullptr,
        512, 512,512,2048, 0,0,0,0,0,0, 1, 1.f, 1);
    mgemm<64,64><<<dim3(8,64,1),256,0,stream>>>(
        ffnhH,ffnhL, W2TH,W2TL, x, nullptr,nullptr, b2_i, x, (i==3) ? out : nullptr,
        2048, 2048,2048,512, 0,0,0,0,0,0, 1, 1.f, 0);
  }

  attns_final_kernel<<<2304,256,0,stream>>>(attns, out + 12582914LL);
  aux_final_kernel<<<1,1,0,stream>>>(aux, out + 12582912LL);
}

// Round 7
// 2983.507 us; speedup vs baseline: 1.2404x; 1.1975x over previous
//
#include <hip/hip_runtime.h>
#include <hip/hip_bf16.h>

#define DEV __device__ __forceinline__

typedef unsigned short u16;
typedef __attribute__((ext_vector_type(8))) short short8;
typedef __attribute__((ext_vector_type(4))) float floatx4;

DEV float gelu_f(float x){ return 0.5f*x*(1.0f+erff(x*0.7071067811865476f)); }

DEV u16 f2bf(float x){
  union { __hip_bfloat16 h; u16 u; } cv;
  cv.h = __float2bfloat16(x);
  return cv.u;
}
DEV float bf2f(u16 u){
  union { unsigned int u32; float f; } cv;
  cv.u32 = ((unsigned int)u) << 16;
  return cv.f;
}
DEV void split2(float v, u16* H, u16* L, long long i){
  u16 h = f2bf(v); H[i] = h; L[i] = f2bf(v - bf2f(h));
}

// async global->LDS 16B per lane; lds dest = wave-uniform base + lane*16
DEV void stage16(const u16* g, u16* lwave, int lane){
#if __has_builtin(__builtin_amdgcn_global_load_lds)
  __builtin_amdgcn_global_load_lds((const __attribute__((address_space(1))) void*)g,
                                   (__attribute__((address_space(3))) void*)lwave, 16, 0, 0);
#else
  *(short8*)(lwave + (long long)lane*8) = *(const short8*)g;
#endif
}

DEV float blockReduceSum(float v){
  __shared__ float red[4];
  int lane = threadIdx.x & 63, wid = threadIdx.x >> 6;
  #pragma unroll
  for (int off=32; off>0; off>>=1) v += __shfl_down(v, off, 64);
  __syncthreads();
  if (lane==0) red[wid]=v;
  __syncthreads();
  return red[0]+red[1]+red[2]+red[3];
}
DEV float blockReduceMax(float v){
  __shared__ float redm[4];
  int lane = threadIdx.x & 63, wid = threadIdx.x >> 6;
  #pragma unroll
  for (int off=32; off>0; off>>=1) v = fmaxf(v, __shfl_down(v, off, 64));
  __syncthreads();
  if (lane==0) redm[wid]=v;
  __syncthreads();
  return fmaxf(fmaxf(redm[0],redm[1]),fmaxf(redm[2],redm[3]));
}

// ---------------------------------------------------------------------------
// bf16x3 MFMA GEMM on pre-split hi/lo operands (round-3 verified structure).
// K-step 64 = two 32-el LDS panels, ONE barrier pair per 64 K-elements.
// ---------------------------------------------------------------------------
template<int BM, int BN>
__global__ __launch_bounds__(256) void mgemm(
    const u16* __restrict__ AH, const u16* __restrict__ AL,
    const u16* __restrict__ BH, const u16* __restrict__ BL,
    float* __restrict__ C, u16* __restrict__ CH, u16* __restrict__ CL,
    const float* __restrict__ bias, const float* __restrict__ resid,
    float* __restrict__ mirror,
    int K, int lda, int ldb, int ldc,
    long long sA1, long long sA2, long long sB1, long long sB2,
    long long sC1, long long sC2, int B2, float scale, int act)
{
  const int b1 = blockIdx.z / B2, b2 = blockIdx.z % B2;
  const long long aOff = b1*sA1 + b2*sA2;
  const long long bOff = b1*sB1 + b2*sB2;
  const long long cOff = b1*sC1 + b2*sC2;
  AH += aOff; AL += aOff; BH += bOff; BL += bOff;
  if (C) C += cOff;
  if (CH){ CH += cOff; CL += cOff; }
  if (resid) resid += cOff;
  if (mirror) mirror += cOff;

  const int m0 = blockIdx.y*BM, n0 = blockIdx.x*BN;
  const int tid = threadIdx.x, lane = tid & 63, wid = tid >> 6;
  const int ln15 = lane & 15, quad = lane >> 4;
  constexpr int WM = BM/2, WN = BN/2, FM = WM/16, FN = WN/16;
  constexpr int RWA = BM/4, RWB = BN/4;
  constexpr int NIA = BM/64, NIB = BN/64;
  const int wr = wid >> 1, wc = wid & 1;

  __shared__ u16 AsH[2*BM*32];
  __shared__ u16 AsL[2*BM*32];
  __shared__ u16 BsH[2*BN*32];
  __shared__ u16 BsL[2*BN*32];

  floatx4 acc[FM][FN];
  #pragma unroll
  for (int a=0;a<FM;++a)
    #pragma unroll
    for (int b=0;b<FN;++b) acc[a][b] = (floatx4){0.f,0.f,0.f,0.f};

  const int rA = wid*RWA + (lane >> 2), cA = (lane & 3)*8;
  const int rB = wid*RWB + (lane >> 2), cB = (lane & 3)*8;
  const u16* pAH = AH + (long long)(m0 + rA)*lda + cA;
  const u16* pAL = AL + (long long)(m0 + rA)*lda + cA;
  const u16* pBH = BH + (long long)(n0 + rB)*ldb + cB;
  const u16* pBL = BL + (long long)(n0 + rB)*ldb + cB;
  u16* lAH = &AsH[wid*RWA*32];
  u16* lAL = &AsL[wid*RWA*32];
  u16* lBH = &BsH[wid*RWB*32];
  u16* lBL = &BsL[wid*RWB*32];

  for (int k0 = 0; k0 < K; k0 += 64) {
    #pragma unroll
    for (int s=0;s<2;++s){
      #pragma unroll
      for (int j=0;j<NIA;++j){
        stage16(pAH + s*32 + (long long)j*16*lda, lAH + s*BM*32 + j*512, lane);
        stage16(pAL + s*32 + (long long)j*16*lda, lAL + s*BM*32 + j*512, lane);
      }
      #pragma unroll
      for (int j=0;j<NIB;++j){
        stage16(pBH + s*32 + (long long)j*16*ldb, lBH + s*BN*32 + j*512, lane);
        stage16(pBL + s*32 + (long long)j*16*ldb, lBL + s*BN*32 + j*512, lane);
      }
    }
    __syncthreads();

    short8 ah[FM][2], al[FM][2], bh[FN][2], bl[FN][2];
    #pragma unroll
    for (int mi=0; mi<FM; ++mi)
      #pragma unroll
      for (int s=0;s<2;++s){
        const int off = s*BM*32 + (wr*WM + mi*16 + ln15)*32 + quad*8;
        ah[mi][s] = *(const short8*)&AsH[off];
        al[mi][s] = *(const short8*)&AsL[off];
      }
    #pragma unroll
    for (int ni=0; ni<FN; ++ni)
      #pragma unroll
      for (int s=0;s<2;++s){
        const int off = s*BN*32 + (wc*WN + ni*16 + ln15)*32 + quad*8;
        bh[ni][s] = *(const short8*)&BsH[off];
        bl[ni][s] = *(const short8*)&BsL[off];
      }
    #pragma unroll
    for (int mi=0; mi<FM; ++mi)
      #pragma unroll
      for (int ni=0; ni<FN; ++ni){
        floatx4 c = acc[mi][ni];
        #pragma unroll
        for (int s=0;s<2;++s){
          c = __builtin_amdgcn_mfma_f32_16x16x32_bf16(ah[mi][s], bh[ni][s], c, 0,0,0);
          c = __builtin_amdgcn_mfma_f32_16x16x32_bf16(ah[mi][s], bl[ni][s], c, 0,0,0);
          c = __builtin_amdgcn_mfma_f32_16x16x32_bf16(al[mi][s], bh[ni][s], c, 0,0,0);
        }
        acc[mi][ni] = c;
      }
    __syncthreads();
    pAH += 64; pAL += 64; pBH += 64; pBL += 64;
  }

  #pragma unroll
  for (int mi=0; mi<FM; ++mi){
    const int rb = m0 + wr*WM + mi*16 + quad*4;
    #pragma unroll
    for (int ni=0; ni<FN; ++ni){
      const int col = n0 + wc*WN + ni*16 + ln15;
      const float bv = bias ? bias[col] : 0.f;
      #pragma unroll
      for (int r=0; r<4; ++r){
        const long long ci = (long long)(rb+r)*ldc + col;
        float v = acc[mi][ni][r]*scale + bv;
        if (act==1) v = gelu_f(v);
        if (resid) v += resid[ci];
        if (C) C[ci] = v;
        if (CH){ u16 h=f2bf(v); CH[ci]=h; CL[ci]=f2bf(v-bf2f(h)); }
        if (mirror) mirror[ci] = v;
      }
    }
  }
}

// ---------------------------------------------------------------------------
// Fused main attention: per block (qtile, z=b*8+h): O = softmax(qK^T/8)V for
// 64 q-rows; accumulates probabilities into attns via atomicAdd.
// 2-pass: pass1 online (m,l) streaming K tiles; pass2 exact P -> attns ->
// P@V with P split hi/lo in-register (same 3-MFMA pattern and t-order as the
// old PV mgemm). Q held in registers; K/V/P tiles in LDS (64KB -> 2 blk/CU).
// ---------------------------------------------------------------------------
__global__ __launch_bounds__(256) void fattn(
    const u16* __restrict__ qH_, const u16* __restrict__ qL_,
    const u16* __restrict__ kvH_, const u16* __restrict__ kvL_,
    const u16* __restrict__ vTH_, const u16* __restrict__ vTL_,
    u16* __restrict__ aoH, u16* __restrict__ aoL,
    float* __restrict__ attns)
{
  const int z = blockIdx.y, b = z >> 3, h = z & 7;
  const int t0 = blockIdx.x * 64;
  const int tid = threadIdx.x, lane = tid & 63, wid = tid >> 6;
  const int ln15 = lane & 15, quad = lane >> 4;

  // each array: 2 panels x [64 rows][32 cols] u16 = 8KB
  __shared__ u16 QsH[4096], QsL[4096], KsH[4096], KsL[4096];
  __shared__ u16 VsH[4096], VsL[4096], PsH[4096], PsL[4096];

  // staging pattern per panel: row = wid*16 + (lane>>2), col = (lane&3)*8
  const int rS = wid*16 + (lane >> 2), cS = (lane & 3)*8;

  // ---- stage Q once; hoist fragments to registers ----
  {
    const u16* qh = qH_ + (long long)(b*512 + t0 + rS)*512 + h*64 + cS;
    const u16* ql = qL_ + (long long)(b*512 + t0 + rS)*512 + h*64 + cS;
    stage16(qh,    &QsH[wid*512], lane);
    stage16(qh+32, &QsH[2048 + wid*512], lane);
    stage16(ql,    &QsL[wid*512], lane);
    stage16(ql+32, &QsL[2048 + wid*512], lane);
  }
  const u16* kHb = kvH_ + (long long)b*1179648 + h*64;
  const u16* kLb = kvL_ + (long long)b*1179648 + h*64;
  const u16* vHb = vTH_ + (long long)z*73728;
  const u16* vLb = vTL_ + (long long)z*73728;
  __syncthreads();

  short8 qfh[2], qfl[2];
  #pragma unroll
  for (int s=0;s<2;++s){
    const int off = s*2048 + (wid*16 + ln15)*32 + quad*8;
    qfh[s] = *(const short8*)&QsH[off];
    qfl[s] = *(const short8*)&QsL[off];
  }

  float m_run[4] = {-3.4e38f,-3.4e38f,-3.4e38f,-3.4e38f};
  float l_run[4] = {0.f,0.f,0.f,0.f};

  // ================= pass 1: online row max & sum =================
  for (int tt = 0; tt < 1152; tt += 64) {
    __syncthreads();   // previous K tile reads complete
    {
      const u16* kh = kHb + (long long)(tt + rS)*1024 + cS;
      const u16* kl = kLb + (long long)(tt + rS)*1024 + cS;
      stage16(kh,    &KsH[wid*512], lane);
      stage16(kh+32, &KsH[2048 + wid*512], lane);
      stage16(kl,    &KsL[wid*512], lane);
      stage16(kl+32, &KsL[2048 + wid*512], lane);
    }
    __syncthreads();

    short8 kh[4][2], kl[4][2];
    #pragma unroll
    for (int ni=0;ni<4;++ni)
      #pragma unroll
      for (int s=0;s<2;++s){
        const int off = s*2048 + (ni*16 + ln15)*32 + quad*8;
        kh[ni][s] = *(const short8*)&KsH[off];
        kl[ni][s] = *(const short8*)&KsL[off];
      }
    floatx4 acc[4];
    #pragma unroll
    for (int ni=0;ni<4;++ni){
      floatx4 c = (floatx4){0.f,0.f,0.f,0.f};
      #pragma unroll
      for (int s=0;s<2;++s){
        c = __builtin_amdgcn_mfma_f32_16x16x32_bf16(qfh[s], kh[ni][s], c, 0,0,0);
        c = __builtin_amdgcn_mfma_f32_16x16x32_bf16(qfh[s], kl[ni][s], c, 0,0,0);
        c = __builtin_amdgcn_mfma_f32_16x16x32_bf16(qfl[s], kh[ni][s], c, 0,0,0);
      }
      acc[ni] = c;
    }
    // per-row (quad*4+r) reduce across cols: in-lane over ni, then xor over ln15
    #pragma unroll
    for (int r=0;r<4;++r){
      float v = fmaxf(fmaxf(acc[0][r],acc[1][r]),fmaxf(acc[2][r],acc[3][r]));
      #pragma unroll
      for (int o=1;o<16;o<<=1) v = fmaxf(v, __shfl_xor(v, o, 64));
      const float mn = fmaxf(m_run[r], 0.125f*v);
      float sum = 0.f;
      #pragma unroll
      for (int ni=0;ni<4;++ni) sum += __expf(0.125f*acc[ni][r] - mn);
      #pragma unroll
      for (int o=1;o<16;o<<=1) sum += __shfl_xor(sum, o, 64);
      l_run[r] = l_run[r]*__expf(m_run[r]-mn) + sum;
      m_run[r] = mn;
    }
  }
  float invl[4];
  #pragma unroll
  for (int r=0;r<4;++r) invl[r] = 1.f/l_run[r];

  // ================= pass 2: P -> attns -> O += P@V =================
  floatx4 o_acc[4];
  #pragma unroll
  for (int ni=0;ni<4;++ni) o_acc[ni] = (floatx4){0.f,0.f,0.f,0.f};

  for (int tt = 0; tt < 1152; tt += 64) {
    __syncthreads();   // previous V/P reads (and pass-1 last K reads) complete
    {
      const u16* kh = kHb + (long long)(tt + rS)*1024 + cS;
      const u16* kl = kLb + (long long)(tt + rS)*1024 + cS;
      stage16(kh,    &KsH[wid*512], lane);
      stage16(kh+32, &KsH[2048 + wid*512], lane);
      stage16(kl,    &KsL[wid*512], lane);
      stage16(kl+32, &KsL[2048 + wid*512], lane);
    }
    __syncthreads();

    short8 kh[4][2], kl[4][2];
    #pragma unroll
    for (int ni=0;ni<4;++ni)
      #pragma unroll
      for (int s=0;s<2;++s){
        const int off = s*2048 + (ni*16 + ln15)*32 + quad*8;
        kh[ni][s] = *(const short8*)&KsH[off];
        kl[ni][s] = *(const short8*)&KsL[off];
      }
    floatx4 acc[4];
    #pragma unroll
    for (int ni=0;ni<4;++ni){
      floatx4 c = (floatx4){0.f,0.f,0.f,0.f};
      #pragma unroll
      for (int s=0;s<2;++s){
        c = __builtin_amdgcn_mfma_f32_16x16x32_bf16(qfh[s], kh[ni][s], c, 0,0,0);
        c = __builtin_amdgcn_mfma_f32_16x16x32_bf16(qfh[s], kl[ni][s], c, 0,0,0);
        c = __builtin_amdgcn_mfma_f32_16x16x32_bf16(qfl[s], kh[ni][s], c, 0,0,0);
      }
      acc[ni] = c;
    }
    // finalize P, accumulate attns, deposit P (hi/lo) into LDS
    const int rowl = wid*16 + quad*4;
    #pragma unroll
    for (int ni=0;ni<4;++ni){
      const int cl = ln15 + ni*16;                     // 0..63 local t
      const int soff = (cl>>5)*2048 + (cl&31);
      #pragma unroll
      for (int r=0;r<4;++r){
        const float p = __expf(0.125f*acc[ni][r] - m_run[r])*invl[r];
        atomicAdd(&attns[(long long)(t0 + rowl + r)*1152 + tt + cl], p);
        const u16 hh = f2bf(p);
        PsH[soff + (rowl+r)*32] = hh;
        PsL[soff + (rowl+r)*32] = f2bf(p - bf2f(hh));
      }
    }
    // stage V tile (vT: [d=64][1152], rows d, cols t)
    {
      const u16* vh = vHb + (long long)rS*1152 + tt + cS;
      const u16* vl = vLb + (long long)rS*1152 + tt + cS;
      stage16(vh,    &VsH[wid*512], lane);
      stage16(vh+32, &VsH[2048 + wid*512], lane);
      stage16(vl,    &VsL[wid*512], lane);
      stage16(vl+32, &VsL[2048 + wid*512], lane);
    }
    __syncthreads();   // V staged + P visible

    short8 pah[2], pal[2], vbh[4][2], vbl[4][2];
    #pragma unroll
    for (int s=0;s<2;++s){
      const int off = s*2048 + (wid*16 + ln15)*32 + quad*8;
      pah[s] = *(const short8*)&PsH[off];
      pal[s] = *(const short8*)&PsL[off];
    }
    #pragma unroll
    for (int ni=0;ni<4;++ni)
      #pragma unroll
      for (int s=0;s<2;++s){
        const int off = s*2048 + (ni*16 + ln15)*32 + quad*8;
        vbh[ni][s] = *(const short8*)&VsH[off];
        vbl[ni][s] = *(const short8*)&VsL[off];
      }
    #pragma unroll
    for (int ni=0;ni<4;++ni){
      floatx4 c = o_acc[ni];
      #pragma unroll
      for (int s=0;s<2;++s){
        c = __builtin_amdgcn_mfma_f32_16x16x32_bf16(pah[s], vbh[ni][s], c, 0,0,0);
        c = __builtin_amdgcn_mfma_f32_16x16x32_bf16(pah[s], vbl[ni][s], c, 0,0,0);
        c = __builtin_amdgcn_mfma_f32_16x16x32_bf16(pal[s], vbh[ni][s], c, 0,0,0);
      }
      o_acc[ni] = c;
    }
  }

  // epilogue: O -> aout H/L
  const int rowl = wid*16 + quad*4;
  #pragma unroll
  for (int ni=0;ni<4;++ni){
    const int col = h*64 + ln15 + ni*16;
    #pragma unroll
    for (int r=0;r<4;++r){
      const long long ci = (long long)(b*512 + t0 + rowl + r)*512 + col;
      split2(o_acc[ni][r], aoH, aoL, ci);
    }
  }
}

// WT H/L [n][k] = split(W[k][n]) ; W is K x N row-major f32
__global__ __launch_bounds__(256) void wtrans_split(
    const float* __restrict__ W, u16* __restrict__ WTH, u16* __restrict__ WTL,
    int K, int N)
{
  __shared__ float t[32][33];
  const int k0 = blockIdx.x*32, n0 = blockIdx.y*32;
  const int r = threadIdx.x >> 5, c = threadIdx.x & 31;
  #pragma unroll
  for (int p=0;p<4;++p) t[r+p*8][c] = W[(long long)(k0+r+p*8)*N + n0+c];
  __syncthreads();
  #pragma unroll
  for (int p=0;p<4;++p){
    const float v = t[c][r+p*8];
    split2(v, WTH, WTL, (long long)(n0+r+p*8)*K + k0+c);
  }
}

// wpermT H/L [o*2048 + r*512 + c] = split(conv_w[o*2048 + c*4 + r])
__global__ __launch_bounds__(256) void wpermT_split(
    const float* __restrict__ w, u16* __restrict__ H, u16* __restrict__ L)
{
  const int idx = blockIdx.x*256 + threadIdx.x; // < 1048576
  const int o = idx >> 11, rem = idx & 2047;
  const int r = rem >> 9, c = rem & 511;
  split2(w[(long long)o*2048 + c*4 + r], H, L, idx);
}

// vT H/L [(b*8+h)*73728 + d*1152 + t] = kvHL[b][t][512 + h*64 + d]
__global__ __launch_bounds__(256) void vtrans_hl(
    const u16* __restrict__ kvH, const u16* __restrict__ kvL,
    u16* __restrict__ vTH, u16* __restrict__ vTL)
{
  const int z = blockIdx.y, t0 = blockIdx.x*64;
  const int b = z >> 3, h = z & 7;
  __shared__ u16 tH[64][72], tL[64][72];
  const int r = threadIdx.x >> 6, c = threadIdx.x & 63;
  #pragma unroll
  for (int p=0;p<16;++p){
    const int row = r + p*4;
    const long long off = (long long)b*1179648 + (long long)(t0+row)*1024 + 512 + h*64 + c;
    tH[row][c] = kvH[off];
    tL[row][c] = kvL[off];
  }
  __syncthreads();
  #pragma unroll
  for (int p=0;p<16;++p){
    const int d = r + p*4;
    const long long o = (long long)z*73728 + (long long)d*1152 + t0 + c;
    vTH[o] = tH[c][d];
    vTL[o] = tL[c][d];
  }
}

// cvT H/L [(b*8+h)*8192 + d*128 + t] = ckvHL[b][t][512 + h*64 + d]
__global__ __launch_bounds__(256) void cvtrans_hl(
    const u16* __restrict__ ckvH, const u16* __restrict__ ckvL,
    u16* __restrict__ cvTH, u16* __restrict__ cvTL)
{
  const int z = blockIdx.y, t0 = blockIdx.x*64;
  const int b = z >> 3, h = z & 7;
  __shared__ u16 tH[64][72], tL[64][72];
  const int r = threadIdx.x >> 6, c = threadIdx.x & 63;
  #pragma unroll
  for (int p=0;p<16;++p){
    const int row = r + p*4;
    const long long off = (long long)b*131072 + (long long)(t0+row)*1024 + 512 + h*64 + c;
    tH[row][c] = ckvH[off];
    tL[row][c] = ckvL[off];
  }
  __syncthreads();
  #pragma unroll
  for (int p=0;p<16;++p){
    const int d = r + p*4;
    const long long o = (long long)z*8192 + (long long)d*128 + t0 + c;
    cvTH[o] = tH[c][d];
    cvTL[o] = tL[c][d];
  }
}

// x[row, d] = embed[seq[row], d] + pe[t, d]
__global__ __launch_bounds__(256) void embed_kernel(
    const int* __restrict__ seq, const float* __restrict__ emb,
    float* __restrict__ x)
{
  const int row = blockIdx.x;
  const int t = row & 511;
  const long long tok = seq[row];
  #pragma unroll
  for (int p = 0; p < 2; ++p) {
    const int d = threadIdx.x + p*256;
    const int j2 = d & ~1;
    const float div = __expf((float)j2 * (-0.0179889460f)); // -ln(10000)/512
    const float ang = (float)t * div;
    const float pe = (d & 1) ? cosf(ang) : sinf(ang);
    x[(long long)row*512 + d] = emb[tok*512 + d] + pe;
  }
}

// LayerNorm -> H/L split output (+ optional f32 mirror for new_mems)
__global__ __launch_bounds__(256) void ln_kernel(
    const float* __restrict__ x, const float* __restrict__ g,
    const float* __restrict__ b, u16* __restrict__ outH, u16* __restrict__ outL,
    float* __restrict__ mirror)
{
  const long long base = (long long)blockIdx.x*512;
  const int tid = threadIdx.x;
  const float v0 = x[base+tid], v1 = x[base+tid+256];
  const float mean = blockReduceSum(v0+v1) * (1.f/512.f);
  const float d0 = v0-mean, d1 = v1-mean;
  const float var = blockReduceSum(d0*d0+d1*d1) * (1.f/512.f);
  const float rstd = rsqrtf(var + 1e-5f);
  const float o0 = d0*rstd*g[tid]     + b[tid];
  const float o1 = d1*rstd*g[tid+256] + b[tid+256];
  split2(o0, outH, outL, base+tid);
  split2(o1, outH, outL, base+tid+256);
  if (mirror) { mirror[base+tid] = o0; mirror[base+tid+256] = o1; }
}

// cm H/L: (b, 640, 512) = [cmems (128) | mems (512)] rows, split
__global__ __launch_bounds__(256) void build_cm_kernel(
    const float* __restrict__ cmems_i, const float* __restrict__ mems_i,
    u16* __restrict__ H, u16* __restrict__ L)
{
  const long long idx = (long long)blockIdx.x*256 + threadIdx.x; // < 2621440
  const int c = (int)(idx & 511);
  const long long rb = idx >> 9;
  const int r = (int)(rb % 640);
  const int b = (int)(rb / 640);
  float v;
  if (r < 128) v = cmems_i[(long long)b*65536 + (long long)r*512 + c];
  else         v = mems_i[(long long)b*262144 + (long long)(r-128)*512 + c];
  split2(v, H, L, idx);
}

// in-place row softmax on H/L pair, single-read/single-write via register row
// cache (MAXP = ceil(Wd/256)).
template<int MAXP>
__global__ __launch_bounds__(256) void softmax_hl(
    u16* __restrict__ H, u16* __restrict__ L, int Wd, float* __restrict__ acc)
{
  const long long base = (long long)blockIdx.x * Wd;
  float v[MAXP];
  float mx = -3.4e38f;
  #pragma unroll
  for (int p = 0; p < MAXP; ++p){
    const int i = threadIdx.x + p*256;
    v[p] = (i < Wd) ? bf2f(H[base+i]) + bf2f(L[base+i]) : -3.4e38f;
    mx = fmaxf(mx, v[p]);
  }
  mx = blockReduceMax(mx);
  float sum = 0.f;
  #pragma unroll
  for (int p = 0; p < MAXP; ++p){
    const int i = threadIdx.x + p*256;
    if (i < Wd){ v[p] = __expf(v[p] - mx); sum += v[p]; }
  }
  sum = blockReduceSum(sum);
  const float inv = 1.f/sum;
  float* arow = acc ? acc + (long long)(blockIdx.x & 511)*Wd : nullptr;
  #pragma unroll
  for (int p = 0; p < MAXP; ++p){
    const int i = threadIdx.x + p*256;
    if (i < Wd){
      const float e = v[p]*inv;
      split2(e, H, L, base+i);
      if (arow) atomicAdd(arow + i, e);
    }
  }
}

__global__ __launch_bounds__(256) void sqdiff_kernel(
    const float* __restrict__ a, const float* __restrict__ b, float* __restrict__ accum)
{
  const int idx0 = blockIdx.x*1024 + threadIdx.x;
  float s = 0.f;
  #pragma unroll
  for (int p = 0; p < 4; ++p) {
    const int idx = idx0 + p*256;
    const float d = a[idx]-b[idx];
    s += d*d;
  }
  s = blockReduceSum(s);
  if (threadIdx.x == 0) atomicAdd(accum, s);
}

__global__ __launch_bounds__(256) void attns_final_kernel(
    const float* __restrict__ asum, float* __restrict__ out)
{
  const int idx = blockIdx.x*256 + threadIdx.x;
  if (idx < 589824) out[idx] = asum[idx]*(1.f/256.f);
}

__global__ void aux_final_kernel(const float* __restrict__ aux, float* __restrict__ out)
{
  out[0] = aux[0] * (1.f/8388608.f);
  out[1] = 0.f;
}

extern "C" void kernel_launch(void* const* d_in, const int* in_sizes, int n_in,
                              void* d_out, int out_size, void* d_ws, size_t ws_size,
                              hipStream_t stream)
{
  const int*   seq    = (const int*)d_in[0];
  // d_in[1] = mask: all-True -> no-op
  const float* mems   = (const float*)d_in[2];
  const float* cmems  = (const float*)d_in[3];
  const float* embed  = (const float*)d_in[4];
  const float* ln1_g  = (const float*)d_in[5];
  const float* ln1_b  = (const float*)d_in[6];
  const float* Wq     = (const float*)d_in[7];
  const float* Wkv    = (const float*)d_in[8];
  const float* Wo     = (const float*)d_in[9];
  const float* bo     = (const float*)d_in[10];
  const float* conv_w = (const float*)d_in[11];
  const float* conv_b = (const float*)d_in[12];
  const float* ln2_g  = (const float*)d_in[13];
  const float* ln2_b  = (const float*)d_in[14];
  const float* W1     = (const float*)d_in[15];
  const float* b1     = (const float*)d_in[16];
  const float* W2     = (const float*)d_in[17];
  const float* b2     = (const float*)d_in[18];
  float* out = (float*)d_out;

  // ---- workspace map (byte offsets), total ~182.7 MB (proven budget 186.9)
  char* W8 = (char*)d_ws;
  float* x     = (float*)(W8 + 0);              // 8,388,608 B
  u16* xnH     = (u16*)(W8 + 8388608LL);        // 4,194,304
  u16* xnL     = (u16*)(W8 + 12582912LL);
  u16* qH      = (u16*)(W8 + 16777216LL);       // 4,194,304 ; xn2H alias
  u16* qL      = (u16*)(W8 + 20971520LL);
  u16* cmH     = (u16*)(W8 + 25165824LL);       // 5,242,880
  u16* cmL     = (u16*)(W8 + 30408704LL);
  u16* kvH     = (u16*)(W8 + 35651584LL);       // 18,874,368 ; ffnhH alias
  u16* kvL     = (u16*)(W8 + 54525952LL);
  u16* vTH     = (u16*)(W8 + 73400320LL);       // 9,437,184
  u16* vTL     = (u16*)(W8 + 82837504LL);
  u16* dotsH   = (u16*)(W8 + 92274688LL);       // 18,874,368
  u16* dotsL   = (u16*)(W8 + 111149056LL);
  u16* aoutH   = (u16*)(W8 + 130023424LL);      // 4,194,304
  u16* aoutL   = (u16*)(W8 + 134217728LL);
  u16* compH   = (u16*)(W8 + 138412032LL);      // 1,048,576
  u16* compL   = (u16*)(W8 + 139460608LL);
  u16* ckvH    = (u16*)(W8 + 140509184LL);      // 2,097,152
  u16* ckvL    = (u16*)(W8 + 142606336LL);
  u16* cvTH    = (u16*)(W8 + 144703488LL);      // 1,048,576
  u16* cvTL    = (u16*)(W8 + 145752064LL);
  u16* wpTH    = (u16*)(W8 + 146800640LL);      // 2,097,152
  u16* wpTL    = (u16*)(W8 + 148897792LL);
  u16* WqTH    = (u16*)(W8 + 150994944LL);      // 524,288 (per-layer)
  u16* WqTL    = (u16*)(W8 + 151519232LL);
  u16* WkvTH   = (u16*)(W8 + 152043520LL);      // 1,048,576
  u16* WkvTL   = (u16*)(W8 + 153092096LL);
  u16* WoTH    = (u16*)(W8 + 154140672LL);      // 524,288
  u16* WoTL    = (u16*)(W8 + 154664960LL);
  u16* W1TH    = (u16*)(W8 + 155189248LL);      // 2,097,152
  u16* W1TL    = (u16*)(W8 + 157286400LL);
  u16* W2TH    = (u16*)(W8 + 159383552LL);      // 2,097,152
  u16* W2TL    = (u16*)(W8 + 161480704LL);
  float* o1    = (float*)(W8 + 163577856LL);    // 8,388,608
  float* o2    = (float*)(W8 + 171966464LL);    // 8,388,608
  float* attns = (float*)(W8 + 180355072LL);    // 2,359,296
  float* aux   = (float*)(W8 + 182714368LL);    // 4
  u16* xn2H = qH;  u16* xn2L = qL;              // q dead before ln2
  u16* ffnhH = kvH; u16* ffnhL = kvL;           // kv dead after aux1

  hipMemsetAsync(attns, 0, 589824*sizeof(float), stream);
  hipMemsetAsync(aux, 0, sizeof(float), stream);

  embed_kernel<<<4096,256,0,stream>>>(seq, embed, x);

  for (int i = 0; i < 4; ++i) {
    const float* bo_i   = bo   + (long long)i*512;
    const float* cw_i   = conv_w + (long long)i*1048576;
    const float* cb_i   = conv_b + (long long)i*512;
    const float* b1_i   = b1   + (long long)i*2048;
    const float* b2_i   = b2   + (long long)i*512;
    const float* mems_i = mems + (long long)i*2097152;
    const float* cmems_i= cmems+ (long long)i*524288;
    float* out_mems_i   = out + 2097152LL  + (long long)i*2097152;
    float* out_cmems_i  = out + 10485760LL + (long long)i*524288;

    // per-layer weight split (N x K hi/lo)
    wtrans_split<<<dim3(16,16),256,0,stream>>>(Wq + (long long)i*262144,  WqTH, WqTL, 512, 512);
    wtrans_split<<<dim3(16,32),256,0,stream>>>(Wkv+ (long long)i*524288,  WkvTH,WkvTL,512, 1024);
    wtrans_split<<<dim3(16,16),256,0,stream>>>(Wo + (long long)i*262144,  WoTH, WoTL, 512, 512);
    wtrans_split<<<dim3(16,64),256,0,stream>>>(W1 + (long long)i*1048576, W1TH, W1TL, 512, 2048);
    wtrans_split<<<dim3(64,16),256,0,stream>>>(W2 + (long long)i*1048576, W2TH, W2TL, 2048,512);

    // xn = LN1(x) -> hi/lo + new_mems f32
    ln_kernel<<<4096,256,0,stream>>>(x, ln1_g+(long long)i*512, ln1_b+(long long)i*512, xnH, xnL, out_mems_i);
    // q = xn @ Wq  (hi/lo out) ; 512 blocks = 2/CU
    mgemm<64,64><<<dim3(8,64,1),256,0,stream>>>(
        xnH,xnL, WqTH,WqTL, nullptr, qH,qL, nullptr,nullptr,nullptr,
        512, 512,512,512, 0,0,0,0,0,0, 1, 1.f, 0);
    // cm = [cmems|mems] split; kv rows 0-639 from cm, rows 640-1151 from xn
    build_cm_kernel<<<10240,256,0,stream>>>(cmems_i, mems_i, cmH, cmL);
    mgemm<64,128><<<dim3(8,10,8),256,0,stream>>>(
        cmH,cmL, WkvTH,WkvTL, nullptr, kvH,kvL, nullptr,nullptr,nullptr,
        512, 512,512,1024, 0,327680, 0,0, 0,1179648, 8, 1.f, 0);
    mgemm<64,128><<<dim3(8,8,8),256,0,stream>>>(
        xnH,xnL, WkvTH,WkvTL, nullptr, kvH+655360,kvL+655360, nullptr,nullptr,nullptr,
        512, 512,512,1024, 0,262144, 0,0, 0,1179648, 8, 1.f, 0);
    // vT (b,h,64,1152) hi/lo
    vtrans_hl<<<dim3(18,64),256,0,stream>>>(kvH, kvL, vTH, vTL);

    // ---- fused main attention (replaces dots GEMM + softmax + PV chain) ----
    fattn<<<dim3(8,64),256,0,stream>>>(qH,qL, kvH,kvL, vTH,vTL, aoutH,aoutL, attns);

    // x = aout @ Wo + bo + x   (f32 residual chain) ; 512 blocks
    mgemm<64,64><<<dim3(8,64,1),256,0,stream>>>(
        aoutH,aoutL, WoTH,WoTL, x, nullptr,nullptr, bo_i, x, nullptr,
        512, 512,512,512, 0,0,0,0,0,0, 1, 1.f, 0);
    // compression: comp = mems(128x2048/b) @ wpermT + conv_b ; 128 blocks
    wpermT_split<<<4096,256,0,stream>>>(cw_i, wpTH, wpTL);
    mgemm<64,64><<<dim3(8,2,8),256,0,stream>>>(
        cmH+65536, cmL+65536, wpTH, wpTL, out_cmems_i, compH, compL, cb_i, nullptr, nullptr,
        2048, 2048,2048,512, 0,327680, 0,0, 0,65536, 8, 1.f, 0);
    // ckv = comp @ Wkv (hi/lo) ; 256 blocks
    mgemm<64,64><<<dim3(16,16,1),256,0,stream>>>(
        compH,compL, WkvTH,WkvTL, nullptr, ckvH,ckvL, nullptr,nullptr,nullptr,
        512, 512,512,1024, 0,0,0,0,0,0, 1, 1.f, 0);
    cvtrans_hl<<<dim3(2,64),256,0,stream>>>(ckvH, ckvL, cvTH, cvTL);
    // aux attn 1 (old-mem K/V), 4 chunks of 16 z ; dots 512 blocks
    for (int c = 0; c < 4; ++c) {
      mgemm<64,128><<<dim3(4,8,16),256,0,stream>>>(
          qH + (long long)c*524288, qL + (long long)c*524288,
          kvH + (long long)c*2359296 + 131072, kvL + (long long)c*2359296 + 131072,
          nullptr, dotsH, dotsL, nullptr,nullptr,nullptr,
          64, 512,1024,512, 262144,64, 1179648,64, 2097152,262144, 8, 0.125f, 0);
      softmax_hl<2><<<8192,256,0,stream>>>(dotsH, dotsL, 512, nullptr);
      mgemm<64,64><<<dim3(1,8,16),256,0,stream>>>(
          dotsH, dotsL, vTH + (long long)c*1179648 + 128, vTL + (long long)c*1179648 + 128,
          o1 + (long long)c*524288, nullptr,nullptr, nullptr,nullptr,nullptr,
          512, 512,1152,64, 2097152,262144, 589824,73728, 262144,32768, 8, 1.f, 0);
    }
    // aux attn 2 (compressed K/V), all 64 z ; 512 blocks
    mgemm<64,128><<<dim3(1,8,64),256,0,stream>>>(
        qH,qL, ckvH,ckvL, nullptr, dotsH, dotsL, nullptr,nullptr,nullptr,
        64, 512,1024,128, 262144,64, 131072,64, 524288,65536, 8, 0.125f, 0);
    softmax_hl<1><<<32768,256,0,stream>>>(dotsH, dotsL, 128, nullptr);
    mgemm<64,64><<<dim3(1,8,64),256,0,stream>>>(
        dotsH, dotsL, cvTH, cvTL, o2, nullptr,nullptr, nullptr,nullptr,nullptr,
        128, 128,128,64, 524288,65536, 65536,8192, 262144,32768, 8, 1.f, 0);
    sqdiff_kernel<<<2048,256,0,stream>>>(o1, o2, aux);
    // FFN
    ln_kernel<<<4096,256,0,stream>>>(x, ln2_g+(long long)i*512, ln2_b+(long long)i*512, xn2H, xn2L, nullptr);
    mgemm<64,128><<<dim3(16,64,1),256,0,stream>>>(
        xn2H,xn2L, W1TH,W1TL, nullptr, ffnhH,ffnhL, b1_i, nullptr, nullptr,
        512, 512,512,2048, 0,0,0,0,0,0, 1, 1.f, 1);
    mgemm<64,64><<<dim3(8,64,1),256,0,stream>>>(
        ffnhH,ffnhL, W2TH,W2TL, x, nullptr,nullptr, b2_i, x, (i==3) ? out : nullptr,
        2048, 2048,2048,512, 0,0,0,0,0,0, 1, 1.f, 0);
  }

  attns_final_kernel<<<2304,256,0,stream>>>(attns, out + 12582914LL);
  aux_final_kernel<<<1,1,0,stream>>>(aux, out + 12582912LL);
}